// Round 1
// baseline (4956.259 us; speedup 1.0000x reference)
//
#include <hip/hip_runtime.h>
#include <math.h>

// Problem constants: x [4, 256, 64, 64] fp32
#define BB   4
#define CC   256
#define NN   4096      // 64*64 spatial
#define GG   8
#define CPG  32        // channels per group
#define EPSV 1e-5f
#define SCALE 0.0625f  // 1/sqrt(256)

// ---------------------------------------------------------------------------
// K1: GroupNorm statistics. One block per (b, g). Reduces 32*4096 = 131072
// elements -> mean, rstd. Group channels are contiguous: base = bg*CPG*NN.
// ---------------------------------------------------------------------------
__global__ __launch_bounds__(256) void gn_stats_kernel(const float* __restrict__ x,
                                                       float* __restrict__ stats) {
    const int bg = blockIdx.x;             // 0..31  (b*8+g)
    const float4* base = (const float4*)(x + (size_t)bg * CPG * NN);
    const int nvec = CPG * NN / 4;         // 32768 float4
    const int tid = threadIdx.x;

    float s = 0.f, sq = 0.f;
    for (int i = tid; i < nvec; i += 256) {
        float4 v = base[i];
        s  += v.x + v.y + v.z + v.w;
        sq += v.x*v.x + v.y*v.y + v.z*v.z + v.w*v.w;
    }
    __shared__ float ls[256], lq[256];
    ls[tid] = s; lq[tid] = sq;
    __syncthreads();
    for (int off = 128; off > 0; off >>= 1) {
        if (tid < off) { ls[tid] += ls[tid+off]; lq[tid] += lq[tid+off]; }
        __syncthreads();
    }
    if (tid == 0) {
        const float cnt = (float)(CPG * NN);
        float mean = ls[0] / cnt;
        float var  = lq[0] / cnt - mean * mean;
        stats[bg*2]   = mean;
        stats[bg*2+1] = rsqrtf(var + EPSV);
    }
}

// ---------------------------------------------------------------------------
// K2: QKV GEMM with GN fused on the B-operand.
// qkv[o][n] = sum_c w_qkv[o][c] * (x[b][c][n]*sc[c] + sh[c]) + bias[o]
// 64x64 tile, K-chunks of 16, fp32. Output written TRANSPOSED into
// q_t/k_t/v_t [b][n][256] so attention rows are contiguous.
// grid: (NN/64, 768/64, BB)
// ---------------------------------------------------------------------------
__global__ __launch_bounds__(256) void qkv_gemm_kernel(
    const float* __restrict__ x, const float* __restrict__ gamma,
    const float* __restrict__ beta, const float* __restrict__ w_qkv,
    const float* __restrict__ b_qkv, const float* __restrict__ stats,
    float* __restrict__ qt, float* __restrict__ kt, float* __restrict__ vt)
{
    const int n0 = blockIdx.x * 64;
    const int o0 = blockIdx.y * 64;
    const int b  = blockIdx.z;
    const int tid = threadIdx.x;

    __shared__ float At[64][17];
    __shared__ float Bt[16][68];
    __shared__ float s_sc[CC], s_sh[CC];

    {   // per-channel scale/shift for fused groupnorm
        int c = tid;
        float mean = stats[(b*GG + c/CPG)*2];
        float rstd = stats[(b*GG + c/CPG)*2 + 1];
        float g = gamma[c], be = beta[c];
        s_sc[c] = rstd * g;
        s_sh[c] = be - mean * rstd * g;
    }
    __syncthreads();

    float acc[4][4] = {};
    const int to = tid / 16, tn = tid % 16;

    for (int c0 = 0; c0 < CC; c0 += 16) {
        {   // A tile 64x16
            int cl = tid % 16, ol = tid / 16;
            for (int r = 0; r < 4; r++)
                At[ol + r*16][cl] = w_qkv[(size_t)(o0 + ol + r*16)*CC + c0 + cl];
        }
        {   // B tile 16x64 with fused normalization
            int nl = tid % 64, cl0 = tid / 64;
            for (int r = 0; r < 4; r++) {
                int cl = cl0 + r*4;
                int c  = c0 + cl;
                float xv = x[((size_t)(b*CC + c))*NN + n0 + nl];
                Bt[cl][nl] = xv * s_sc[c] + s_sh[c];
            }
        }
        __syncthreads();
        for (int kk = 0; kk < 16; kk++) {
            float a[4];
            for (int i = 0; i < 4; i++) a[i] = At[to*4 + i][kk];
            float4 bv = *(const float4*)&Bt[kk][tn*4];
            float bb[4] = {bv.x, bv.y, bv.z, bv.w};
            for (int i = 0; i < 4; i++)
                for (int j = 0; j < 4; j++)
                    acc[i][j] += a[i] * bb[j];
        }
        __syncthreads();
    }

    for (int i = 0; i < 4; i++) {
        int o = o0 + to*4 + i;
        float bias = b_qkv[o];
        int which = o >> 8;         // 0:q 1:k 2:v
        int oc = o & 255;
        float* dst = (which == 0) ? qt : ((which == 1) ? kt : vt);
        for (int j = 0; j < 4; j++) {
            int n = n0 + tn*4 + j;
            dst[((size_t)b*NN + n)*CC + oc] = acc[i][j] + bias;
        }
    }
}

// ---------------------------------------------------------------------------
// K3: fused flash-style attention (fp32). One wave per 4 query rows.
// Each lane holds 4 channels (float4). Per key j: coalesced k/v row loads,
// 4 dots + 64-lane butterfly reduce, online softmax, PV accumulate in regs.
// grid: BB * NN/16, block 256 (4 waves * 4 rows = 16 rows/block)
// ---------------------------------------------------------------------------
__global__ __launch_bounds__(256) void attn_kernel(
    const float* __restrict__ qt, const float* __restrict__ kt,
    const float* __restrict__ vt, float* __restrict__ ao)
{
    const int tid  = threadIdx.x;
    const int wave = tid >> 6, lane = tid & 63;
    const int blk  = blockIdx.x;
    const int b    = blk >> 8;                 // / (NN/16 = 256)
    const int i0   = (blk & 255)*16 + wave*4;

    float4 qf[4];
    for (int r = 0; r < 4; r++)
        qf[r] = *(const float4*)(qt + ((size_t)b*NN + i0 + r)*CC + lane*4);

    float m[4], l[4];
    float4 acc[4];
    for (int r = 0; r < 4; r++) {
        m[r] = -INFINITY; l[r] = 0.f;
        acc[r] = make_float4(0.f, 0.f, 0.f, 0.f);
    }

    const float* kb = kt + (size_t)b*NN*CC;
    const float* vb = vt + (size_t)b*NN*CC;

    for (int j = 0; j < NN; j++) {
        float4 kf = *(const float4*)(kb + (size_t)j*CC + lane*4);
        float4 vf = *(const float4*)(vb + (size_t)j*CC + lane*4);
        float s[4];
        for (int r = 0; r < 4; r++) {
            float p = qf[r].x*kf.x + qf[r].y*kf.y + qf[r].z*kf.z + qf[r].w*kf.w;
            p += __shfl_xor(p, 32);
            p += __shfl_xor(p, 16);
            p += __shfl_xor(p, 8);
            p += __shfl_xor(p, 4);
            p += __shfl_xor(p, 2);
            p += __shfl_xor(p, 1);
            s[r] = p * SCALE;
        }
        for (int r = 0; r < 4; r++) {
            float mn   = fmaxf(m[r], s[r]);
            float corr = __expf(m[r] - mn);
            float p    = __expf(s[r] - mn);
            l[r] = l[r]*corr + p;
            acc[r].x = acc[r].x*corr + p*vf.x;
            acc[r].y = acc[r].y*corr + p*vf.y;
            acc[r].z = acc[r].z*corr + p*vf.z;
            acc[r].w = acc[r].w*corr + p*vf.w;
            m[r] = mn;
        }
    }

    for (int r = 0; r < 4; r++) {
        float inv = 1.0f / l[r];
        float4 o = make_float4(acc[r].x*inv, acc[r].y*inv, acc[r].z*inv, acc[r].w*inv);
        *(float4*)(ao + ((size_t)b*NN + i0 + r)*CC + lane*4) = o;
    }
}

// ---------------------------------------------------------------------------
// K4: proj (NT GEMM) + bias + residual.
// out[b][o][n] = sum_c w_proj[o][c]*ao[b][n][c] + b_proj[o] + x[b][o][n]
// grid: (NN/64, CC/64, BB)
// ---------------------------------------------------------------------------
__global__ __launch_bounds__(256) void proj_kernel(
    const float* __restrict__ ao, const float* __restrict__ w_proj,
    const float* __restrict__ b_proj, const float* __restrict__ x,
    float* __restrict__ out)
{
    const int n0 = blockIdx.x * 64;
    const int o0 = blockIdx.y * 64;
    const int b  = blockIdx.z;
    const int tid = threadIdx.x;

    __shared__ float At[64][17];   // w_proj tile [o][c]
    __shared__ float Bt[64][17];   // ao tile [n][c]

    const int to = tid / 16, tn = tid % 16;
    float acc[4][4] = {};

    for (int c0 = 0; c0 < CC; c0 += 16) {
        int cl = tid % 16, rl = tid / 16;
        for (int r = 0; r < 4; r++)
            At[rl + r*16][cl] = w_proj[(size_t)(o0 + rl + r*16)*CC + c0 + cl];
        for (int r = 0; r < 4; r++)
            Bt[rl + r*16][cl] = ao[((size_t)b*NN + n0 + rl + r*16)*CC + c0 + cl];
        __syncthreads();
        for (int kk = 0; kk < 16; kk++) {
            float a[4], bb[4];
            for (int i = 0; i < 4; i++) a[i]  = At[to*4 + i][kk];
            for (int i = 0; i < 4; i++) bb[i] = Bt[tn*4 + i][kk];
            for (int i = 0; i < 4; i++)
                for (int j = 0; j < 4; j++)
                    acc[i][j] += a[i] * bb[j];
        }
        __syncthreads();
    }

    for (int i = 0; i < 4; i++) {
        int o = o0 + to*4 + i;
        float bias = b_proj[o];
        for (int j = 0; j < 4; j++) {
            int n = n0 + tn*4 + j;
            size_t idx = ((size_t)(b*CC + o))*NN + n;
            out[idx] = acc[i][j] + bias + x[idx];
        }
    }
}

// ---------------------------------------------------------------------------
extern "C" void kernel_launch(void* const* d_in, const int* in_sizes, int n_in,
                              void* d_out, int out_size, void* d_ws, size_t ws_size,
                              hipStream_t stream) {
    const float* x      = (const float*)d_in[0];
    const float* gamma  = (const float*)d_in[1];
    const float* beta   = (const float*)d_in[2];
    const float* w_qkv  = (const float*)d_in[3];
    const float* b_qkv  = (const float*)d_in[4];
    const float* w_proj = (const float*)d_in[5];
    const float* b_proj = (const float*)d_in[6];
    float* out = (float*)d_out;

    // workspace layout (floats): qt | kt | vt | ao | stats
    const size_t plane = (size_t)BB * NN * CC;   // 4,194,304 floats
    float* ws = (float*)d_ws;
    float* qt    = ws;
    float* kt    = qt + plane;
    float* vt    = kt + plane;
    float* ao    = vt + plane;
    float* stats = ao + plane;                   // 64 floats

    gn_stats_kernel<<<BB*GG, 256, 0, stream>>>(x, stats);

    dim3 g2(NN/64, (3*CC)/64, BB);
    qkv_gemm_kernel<<<g2, 256, 0, stream>>>(x, gamma, beta, w_qkv, b_qkv,
                                            stats, qt, kt, vt);

    attn_kernel<<<BB*NN/16, 256, 0, stream>>>(qt, kt, vt, ao);

    dim3 g4(NN/64, CC/64, BB);
    proj_kernel<<<g4, 256, 0, stream>>>(ao, w_proj, b_proj, x, out);
}

// Round 2
// 507.940 us; speedup vs baseline: 9.7576x; 9.7576x over previous
//
#include <hip/hip_runtime.h>
#include <math.h>

// Problem constants: x [4, 256, 64, 64] fp32
#define BB   4
#define CC   256
#define NN   4096      // 64*64 spatial
#define GG   8
#define CPG  32        // channels per group
#define EPSV 1e-5f
#define SCALE 0.0625f  // 1/sqrt(256)

typedef __attribute__((ext_vector_type(8))) short bf16x8;  // 8 bf16 = 4 VGPRs
typedef __attribute__((ext_vector_type(4))) float f32x4;

static __device__ __forceinline__ unsigned short f2bf(float f) {
    union { float f; unsigned int u; } a; a.f = f;
    unsigned int r = a.u + 0x7fffu + ((a.u >> 16) & 1u);   // RNE
    return (unsigned short)(r >> 16);
}

// ---------------------------------------------------------------------------
// K1: GroupNorm statistics. One block per (b, g).
// ---------------------------------------------------------------------------
__global__ __launch_bounds__(256) void gn_stats_kernel(const float* __restrict__ x,
                                                       float* __restrict__ stats) {
    const int bg = blockIdx.x;             // 0..31  (b*8+g)
    const float4* base = (const float4*)(x + (size_t)bg * CPG * NN);
    const int nvec = CPG * NN / 4;
    const int tid = threadIdx.x;

    float s = 0.f, sq = 0.f;
    for (int i = tid; i < nvec; i += 256) {
        float4 v = base[i];
        s  += v.x + v.y + v.z + v.w;
        sq += v.x*v.x + v.y*v.y + v.z*v.z + v.w*v.w;
    }
    __shared__ float ls[256], lq[256];
    ls[tid] = s; lq[tid] = sq;
    __syncthreads();
    for (int off = 128; off > 0; off >>= 1) {
        if (tid < off) { ls[tid] += ls[tid+off]; lq[tid] += lq[tid+off]; }
        __syncthreads();
    }
    if (tid == 0) {
        const float cnt = (float)(CPG * NN);
        float mean = ls[0] / cnt;
        float var  = lq[0] / cnt - mean * mean;
        stats[bg*2]   = mean;
        stats[bg*2+1] = rsqrtf(var + EPSV);
    }
}

// ---------------------------------------------------------------------------
// K2: QKV GEMM with GN fused on B-operand. Outputs bf16:
//   qt [b][n][256] (attention scale folded in), kt [b][n][256],
//   vt [b][256][n]  (channel-major -> LDS-stageable for PV B-frags)
// grid: (NN/64, 768/64, BB), block 256
// ---------------------------------------------------------------------------
__global__ __launch_bounds__(256) void qkv_gemm_kernel(
    const float* __restrict__ x, const float* __restrict__ gamma,
    const float* __restrict__ beta, const float* __restrict__ w_qkv,
    const float* __restrict__ b_qkv, const float* __restrict__ stats,
    unsigned short* __restrict__ qt, unsigned short* __restrict__ kt,
    unsigned short* __restrict__ vt)
{
    const int n0 = blockIdx.x * 64;
    const int o0 = blockIdx.y * 64;
    const int b  = blockIdx.z;
    const int tid = threadIdx.x;

    __shared__ float At[64][17];
    __shared__ float Bt[16][68];
    __shared__ float s_sc[CC], s_sh[CC];

    {
        int c = tid;
        float mean = stats[(b*GG + c/CPG)*2];
        float rstd = stats[(b*GG + c/CPG)*2 + 1];
        float g = gamma[c], be = beta[c];
        s_sc[c] = rstd * g;
        s_sh[c] = be - mean * rstd * g;
    }
    __syncthreads();

    float acc[4][4] = {};
    const int to = tid / 16, tn = tid % 16;

    for (int c0 = 0; c0 < CC; c0 += 16) {
        {
            int cl = tid % 16, ol = tid / 16;
            for (int r = 0; r < 4; r++)
                At[ol + r*16][cl] = w_qkv[(size_t)(o0 + ol + r*16)*CC + c0 + cl];
        }
        {
            int nl = tid % 64, cl0 = tid / 64;
            for (int r = 0; r < 4; r++) {
                int cl = cl0 + r*4;
                int c  = c0 + cl;
                float xv = x[((size_t)(b*CC + c))*NN + n0 + nl];
                Bt[cl][nl] = xv * s_sc[c] + s_sh[c];
            }
        }
        __syncthreads();
        for (int kk = 0; kk < 16; kk++) {
            float a[4];
            for (int i = 0; i < 4; i++) a[i] = At[to*4 + i][kk];
            float4 bv = *(const float4*)&Bt[kk][tn*4];
            float bb[4] = {bv.x, bv.y, bv.z, bv.w};
            for (int i = 0; i < 4; i++)
                for (int j = 0; j < 4; j++)
                    acc[i][j] += a[i] * bb[j];
        }
        __syncthreads();
    }

    for (int i = 0; i < 4; i++) {
        int o = o0 + to*4 + i;
        float bias = b_qkv[o];
        int which = o >> 8;         // 0:q 1:k 2:v
        int oc = o & 255;
        for (int j = 0; j < 4; j++) {
            int n = n0 + tn*4 + j;
            float val = acc[i][j] + bias;
            if (which == 0) {
                qt[((size_t)(b*NN + n))*CC + oc] = f2bf(val * SCALE);
            } else if (which == 1) {
                kt[((size_t)(b*NN + n))*CC + oc] = f2bf(val);
            } else {
                vt[((size_t)(b*CC + oc))*NN + n] = f2bf(val);
            }
        }
    }
}

// ---------------------------------------------------------------------------
// K3: MFMA flash attention, bf16 inputs, fp32 accum.
// Workgroup = 256 threads (4 waves), wave owns 16 Q rows. Grid = BB*64 = 256.
// j-loop over K/V tiles of BC=32, staged in LDS with bank-uniform padding.
// S via mfma_f32_16x16x32_bf16 (C/D: col=lane&15, row=quad*4+reg).
// P transits per-wave LDS (C-layout -> A-layout). O accum 16x256 fp32/wave.
// ---------------------------------------------------------------------------
#define BC 32
#define KSTR 264   // ldsK row stride (ushort): 528B, 16B-aligned, bank-uniform
#define VSTR 40    // ldsV row stride (ushort): 80B,  16B-aligned, bank-uniform
#define PSTR 40    // ldsP row stride

__global__ __launch_bounds__(256) void attn_mfma_kernel(
    const unsigned short* __restrict__ qt, const unsigned short* __restrict__ kt,
    const unsigned short* __restrict__ vt, float* __restrict__ ao)
{
    const int tid  = threadIdx.x;
    const int wave = tid >> 6, lane = tid & 63;
    const int b    = blockIdx.x >> 6;
    const int iblk = blockIdx.x & 63;
    const int i0   = iblk*64 + wave*16;

    __shared__ unsigned short ldsK[32*KSTR];      // 16896 B
    __shared__ unsigned short ldsV[256*VSTR];     // 20480 B
    __shared__ unsigned short ldsP[4][16*PSTR];   //  5120 B

    const int lrow = lane & 15;
    const int quad = lane >> 4;

    // Q A-fragments: qf[kk] covers channels kk*32 + quad*8 .. +8 of row i0+lrow
    bf16x8 qf[8];
    {
        const unsigned short* qbase = qt + ((size_t)(b*NN + i0 + lrow))*CC + quad*8;
        for (int kk = 0; kk < 8; kk++) qf[kk] = *(const bf16x8*)(qbase + kk*32);
    }

    f32x4 o_acc[16];
    for (int t = 0; t < 16; t++) o_acc[t] = (f32x4){0.f, 0.f, 0.f, 0.f};
    float m_r[4], l_r[4];
    for (int r = 0; r < 4; r++) { m_r[r] = -1e30f; l_r[r] = 0.f; }

    const unsigned short* kbB = kt + (size_t)b*NN*CC;
    const unsigned short* vbB = vt + (size_t)b*CC*NN;

    for (int j0 = 0; j0 < NN; j0 += BC) {
        // ---- stage K tile [32][256] and V tile [256][32] into LDS (16B chunks)
        {
            const unsigned short* src = kbB + (size_t)j0*CC;
            for (int t = 0; t < 4; t++) {
                int L = tid + t*256;               // 0..1023
                int j = L >> 5, part = L & 31;
                bf16x8 v = *(const bf16x8*)(src + j*CC + part*8);
                *(bf16x8*)(&ldsK[j*KSTR + part*8]) = v;
            }
            const unsigned short* vsrc = vbB + j0;
            for (int t = 0; t < 4; t++) {
                int L = tid + t*256;
                int c = L >> 2, part = L & 3;
                bf16x8 v = *(const bf16x8*)(vsrc + (size_t)c*NN + part*8);
                *(bf16x8*)(&ldsV[c*VSTR + part*8]) = v;
            }
        }
        __syncthreads();

        // ---- S = Q K^T (scale pre-folded into q): 2 j-subtiles of 16
        f32x4 s[2];
        for (int js = 0; js < 2; js++) {
            f32x4 acc = (f32x4){0.f, 0.f, 0.f, 0.f};
            const unsigned short* kb = &ldsK[(js*16 + lrow)*KSTR + quad*8];
            for (int kk = 0; kk < 8; kk++) {
                bf16x8 kf = *(const bf16x8*)(kb + kk*32);
                acc = __builtin_amdgcn_mfma_f32_16x16x32_bf16(qf[kk], kf, acc, 0, 0, 0);
            }
            s[js] = acc;
        }

        // ---- online softmax (row = quad*4 + r, spread over 16 lanes of quad)
        float alpha[4];
        for (int r = 0; r < 4; r++) {
            float mx = fmaxf(s[0][r], s[1][r]);
            mx = fmaxf(mx, __shfl_xor(mx, 1));
            mx = fmaxf(mx, __shfl_xor(mx, 2));
            mx = fmaxf(mx, __shfl_xor(mx, 4));
            mx = fmaxf(mx, __shfl_xor(mx, 8));
            float mnew = fmaxf(m_r[r], mx);
            alpha[r] = __expf(m_r[r] - mnew);
            float p0 = __expf(s[0][r] - mnew);
            float p1 = __expf(s[1][r] - mnew);
            s[0][r] = p0; s[1][r] = p1;
            float sum = p0 + p1;
            sum += __shfl_xor(sum, 1);
            sum += __shfl_xor(sum, 2);
            sum += __shfl_xor(sum, 4);
            sum += __shfl_xor(sum, 8);
            l_r[r] = l_r[r]*alpha[r] + sum;
            m_r[r] = mnew;
        }

        // P -> per-wave LDS in [i-row][j-col] layout (bf16)
        unsigned short* pw = ldsP[wave];
        for (int js = 0; js < 2; js++)
            for (int r = 0; r < 4; r++)
                pw[(quad*4 + r)*PSTR + js*16 + lrow] = f2bf(s[js][r]);

        // rescale O accumulators
        for (int t = 0; t < 16; t++)
            for (int r = 0; r < 4; r++)
                o_acc[t][r] *= alpha[r];

        // ---- PV: A-frag = P[lrow][quad*8+t], B-frag = V[j=quad*8+t][ch]
        bf16x8 pa = *(const bf16x8*)(&pw[lrow*PSTR + quad*8]);
        for (int nsub = 0; nsub < 16; nsub++) {
            bf16x8 vf = *(const bf16x8*)(&ldsV[(nsub*16 + lrow)*VSTR + quad*8]);
            o_acc[nsub] = __builtin_amdgcn_mfma_f32_16x16x32_bf16(pa, vf, o_acc[nsub], 0, 0, 0);
        }
        __syncthreads();
    }

    // epilogue: normalize rows, write ao [b][n][256] fp32
    float inv[4];
    for (int r = 0; r < 4; r++) inv[r] = 1.0f / l_r[r];
    float* aobase = ao + ((size_t)(b*NN + i0))*CC;
    for (int nsub = 0; nsub < 16; nsub++)
        for (int r = 0; r < 4; r++)
            aobase[(size_t)(quad*4 + r)*CC + nsub*16 + lrow] = o_acc[nsub][r] * inv[r];
}

// ---------------------------------------------------------------------------
// K4: proj (NT GEMM) + bias + residual.
// ---------------------------------------------------------------------------
__global__ __launch_bounds__(256) void proj_kernel(
    const float* __restrict__ ao, const float* __restrict__ w_proj,
    const float* __restrict__ b_proj, const float* __restrict__ x,
    float* __restrict__ out)
{
    const int n0 = blockIdx.x * 64;
    const int o0 = blockIdx.y * 64;
    const int b  = blockIdx.z;
    const int tid = threadIdx.x;

    __shared__ float At[64][17];
    __shared__ float Bt[64][17];

    const int to = tid / 16, tn = tid % 16;
    float acc[4][4] = {};

    for (int c0 = 0; c0 < CC; c0 += 16) {
        int cl = tid % 16, rl = tid / 16;
        for (int r = 0; r < 4; r++)
            At[rl + r*16][cl] = w_proj[(size_t)(o0 + rl + r*16)*CC + c0 + cl];
        for (int r = 0; r < 4; r++)
            Bt[rl + r*16][cl] = ao[((size_t)b*NN + n0 + rl + r*16)*CC + c0 + cl];
        __syncthreads();
        for (int kk = 0; kk < 16; kk++) {
            float a[4], bb[4];
            for (int i = 0; i < 4; i++) a[i]  = At[to*4 + i][kk];
            for (int i = 0; i < 4; i++) bb[i] = Bt[tn*4 + i][kk];
            for (int i = 0; i < 4; i++)
                for (int j = 0; j < 4; j++)
                    acc[i][j] += a[i] * bb[j];
        }
        __syncthreads();
    }

    for (int i = 0; i < 4; i++) {
        int o = o0 + to*4 + i;
        float bias = b_proj[o];
        for (int j = 0; j < 4; j++) {
            int n = n0 + tn*4 + j;
            size_t idx = ((size_t)(b*CC + o))*NN + n;
            out[idx] = acc[i][j] + bias + x[idx];
        }
    }
}

// ---------------------------------------------------------------------------
extern "C" void kernel_launch(void* const* d_in, const int* in_sizes, int n_in,
                              void* d_out, int out_size, void* d_ws, size_t ws_size,
                              hipStream_t stream) {
    const float* x      = (const float*)d_in[0];
    const float* gamma  = (const float*)d_in[1];
    const float* beta   = (const float*)d_in[2];
    const float* w_qkv  = (const float*)d_in[3];
    const float* b_qkv  = (const float*)d_in[4];
    const float* w_proj = (const float*)d_in[5];
    const float* b_proj = (const float*)d_in[6];
    float* out = (float*)d_out;

    // workspace layout: qt | kt | vt (bf16 planes) | ao (fp32) | stats
    const size_t plane = (size_t)BB * NN * CC;   // 4,194,304 elems
    unsigned short* qt = (unsigned short*)d_ws;
    unsigned short* kt = qt + plane;
    unsigned short* vt = kt + plane;
    float* ao    = (float*)(vt + plane);
    float* stats = ao + plane;

    gn_stats_kernel<<<BB*GG, 256, 0, stream>>>(x, stats);

    dim3 g2(NN/64, (3*CC)/64, BB);
    qkv_gemm_kernel<<<g2, 256, 0, stream>>>(x, gamma, beta, w_qkv, b_qkv,
                                            stats, qt, kt, vt);

    attn_mfma_kernel<<<BB*64, 256, 0, stream>>>(qt, kt, vt, ao);

    dim3 g4(NN/64, CC/64, BB);
    proj_kernel<<<g4, 256, 0, stream>>>(ao, w_proj, b_proj, x, out);
}

// Round 3
// 365.382 us; speedup vs baseline: 13.5646x; 1.3902x over previous
//
#include <hip/hip_runtime.h>
#include <math.h>

// Problem constants: x [4, 256, 64, 64] fp32
#define BB   4
#define CC   256
#define NN   4096      // 64*64 spatial
#define GG   8
#define CPG  32        // channels per group
#define EPSV 1e-5f
#define SCALE 0.0625f  // 1/sqrt(256)
#define NSPLIT 2

typedef __attribute__((ext_vector_type(8))) short bf16x8;  // 8 bf16 = 4 VGPRs
typedef __attribute__((ext_vector_type(4))) float f32x4;

struct alignas(8) us4 { unsigned short x, y, z, w; };

static __device__ __forceinline__ unsigned short f2bf(float f) {
    union { float f; unsigned int u; } a; a.f = f;
    unsigned int r = a.u + 0x7fffu + ((a.u >> 16) & 1u);   // RNE
    return (unsigned short)(r >> 16);
}

// ---------------------------------------------------------------------------
// K1: GroupNorm statistics. One block per (b, g).
// ---------------------------------------------------------------------------
__global__ __launch_bounds__(256) void gn_stats_kernel(const float* __restrict__ x,
                                                       float* __restrict__ stats) {
    const int bg = blockIdx.x;             // 0..31  (b*8+g)
    const float4* base = (const float4*)(x + (size_t)bg * CPG * NN);
    const int nvec = CPG * NN / 4;
    const int tid = threadIdx.x;

    float s = 0.f, sq = 0.f;
    for (int i = tid; i < nvec; i += 256) {
        float4 v = base[i];
        s  += v.x + v.y + v.z + v.w;
        sq += v.x*v.x + v.y*v.y + v.z*v.z + v.w*v.w;
    }
    __shared__ float ls[256], lq[256];
    ls[tid] = s; lq[tid] = sq;
    __syncthreads();
    for (int off = 128; off > 0; off >>= 1) {
        if (tid < off) { ls[tid] += ls[tid+off]; lq[tid] += lq[tid+off]; }
        __syncthreads();
    }
    if (tid == 0) {
        const float cnt = (float)(CPG * NN);
        float mean = ls[0] / cnt;
        float var  = lq[0] / cnt - mean * mean;
        stats[bg*2]   = mean;
        stats[bg*2+1] = rsqrtf(var + EPSV);
    }
}

// ---------------------------------------------------------------------------
// K2: QKV GEMM with GN fused on B-operand. Outputs bf16 in MFMA-FRAGMENT
// order (chunk = 64 lanes x 8 elems = 1 KB, linear in lane):
//  q_sw/k_sw chunk(b, jg, kk): lane(q,m) elem j = {Q,K}[jg*16+m][kk*32+q*8+j]
//     (B-frag for S-phase; q_sw has attention scale folded in)
//  v_sw chunk(b, jg2, ns):     lane(q,c) elem j = V[jg2*32+q*8+j][ns*16+c]
//     (B-frag for PV-phase)
// grid: (NN/64, 768/64, BB), block 256
// ---------------------------------------------------------------------------
__global__ __launch_bounds__(256) void qkv_gemm_kernel(
    const float* __restrict__ x, const float* __restrict__ gamma,
    const float* __restrict__ beta, const float* __restrict__ w_qkv,
    const float* __restrict__ b_qkv, const float* __restrict__ stats,
    unsigned short* __restrict__ qsw, unsigned short* __restrict__ ksw,
    unsigned short* __restrict__ vsw)
{
    const int n0 = blockIdx.x * 64;
    const int o0 = blockIdx.y * 64;
    const int b  = blockIdx.z;
    const int tid = threadIdx.x;

    __shared__ float At[64][17];
    __shared__ float Bt[16][68];
    __shared__ float s_sc[CC], s_sh[CC];

    {
        int c = tid;
        float mean = stats[(b*GG + c/CPG)*2];
        float rstd = stats[(b*GG + c/CPG)*2 + 1];
        float g = gamma[c], be = beta[c];
        s_sc[c] = rstd * g;
        s_sh[c] = be - mean * rstd * g;
    }
    __syncthreads();

    float acc[4][4] = {};
    const int to = tid / 16, tn = tid % 16;

    for (int c0 = 0; c0 < CC; c0 += 16) {
        {
            int cl = tid % 16, ol = tid / 16;
            for (int r = 0; r < 4; r++)
                At[ol + r*16][cl] = w_qkv[(size_t)(o0 + ol + r*16)*CC + c0 + cl];
        }
        {
            int nl = tid % 64, cl0 = tid / 64;
            for (int r = 0; r < 4; r++) {
                int cl = cl0 + r*4;
                int c  = c0 + cl;
                float xv = x[((size_t)(b*CC + c))*NN + n0 + nl];
                Bt[cl][nl] = xv * s_sc[c] + s_sh[c];
            }
        }
        __syncthreads();
        for (int kk = 0; kk < 16; kk++) {
            float a[4];
            for (int i = 0; i < 4; i++) a[i] = At[to*4 + i][kk];
            float4 bv = *(const float4*)&Bt[kk][tn*4];
            float bb[4] = {bv.x, bv.y, bv.z, bv.w};
            for (int i = 0; i < 4; i++)
                for (int j = 0; j < 4; j++)
                    acc[i][j] += a[i] * bb[j];
        }
        __syncthreads();
    }

    const int which = o0 >> 8;          // 0:q 1:k 2:v (uniform per block)
    float bias[4];
    for (int i = 0; i < 4; i++) bias[i] = b_qkv[o0 + to*4 + i];

    if (which < 2) {
        unsigned short* dst = (which == 0) ? qsw : ksw;
        const float sc = (which == 0) ? SCALE : 1.0f;
        const int oc0 = (o0 & 255) + to*4;      // 4 consecutive within 8-group
        const int kk = oc0 >> 5, qsel = (oc0 >> 3) & 3, e0 = oc0 & 7;
        for (int j = 0; j < 4; j++) {
            int n = n0 + tn*4 + j;
            size_t off = ((size_t)(b*256 + (n >> 4))*8 + kk)*512
                       + (size_t)(qsel*16 + (n & 15))*8 + e0;
            us4 h;
            h.x = f2bf((acc[0][j] + bias[0]) * sc);
            h.y = f2bf((acc[1][j] + bias[1]) * sc);
            h.z = f2bf((acc[2][j] + bias[2]) * sc);
            h.w = f2bf((acc[3][j] + bias[3]) * sc);
            *(us4*)(dst + off) = h;
        }
    } else {
        const int nb = n0 + tn*4;               // 4 consecutive within 8-group
        for (int i = 0; i < 4; i++) {
            int oc = (o0 & 255) + to*4 + i;
            size_t off = ((size_t)(b*128 + (nb >> 5))*16 + (oc >> 4))*512
                       + (size_t)(((nb >> 3) & 3)*16 + (oc & 15))*8 + (nb & 7);
            us4 h;
            h.x = f2bf(acc[i][0] + bias[i]);
            h.y = f2bf(acc[i][1] + bias[i]);
            h.z = f2bf(acc[i][2] + bias[i]);
            h.w = f2bf(acc[i][3] + bias[i]);
            *(us4*)(vsw + off) = h;
        }
    }
}

// ---------------------------------------------------------------------------
// K3: MFMA flash attention v3. 4 waves/block, 32 Q-rows/wave (128/block),
// split-KV x2 -> grid 256. Frag-linear LDS (conflict-free), fixed-max
// softmax (scores ~N(0,1), max ~6 << 88 overflow), per-lane l partials.
// Outputs UNNORMALIZED o_part + per-row l; combine fused into proj.
// ---------------------------------------------------------------------------
__global__ __launch_bounds__(256, 1) void attn_mfma_kernel(
    const unsigned short* __restrict__ qsw, const unsigned short* __restrict__ ksw,
    const unsigned short* __restrict__ vsw,
    float* __restrict__ opart, float* __restrict__ lpart)
{
    const int tid  = threadIdx.x;
    const int wave = tid >> 6, lane = tid & 63;
    const int lrow = lane & 15, quad = lane >> 4;
    const int bx    = blockIdx.x;
    const int split = bx & 1;
    const int ig    = (bx >> 1) & 31;
    const int b     = bx >> 6;
    const int i0w   = ig*128 + wave*32;          // wave's first q-row
    const int koff  = split * (NN / NSPLIT);     // 0 or 2048
    const int NT    = (NN / NSPLIT) / 32;        // 64 tiles

    __shared__ unsigned short ldsK[16*512];      // 16 KB, chunk-linear
    __shared__ unsigned short ldsV[16*512];      // 16 KB
    __shared__ unsigned short ldsP[4][1024];     //  8 KB (per-wave 32x32)

    // Q A-fragments (rows i0w..i0w+31, all 256 ch): qf[g][kk]
    bf16x8 qf[2][8];
    for (int g = 0; g < 2; g++)
        for (int kk = 0; kk < 8; kk++)
            qf[g][kk] = *(const bf16x8*)(qsw +
                ((size_t)(b*256 + (i0w >> 4) + g)*8 + kk)*512 + lane*8);

    f32x4 o_acc[2][16];
    for (int g = 0; g < 2; g++)
        for (int ns = 0; ns < 16; ns++)
            o_acc[g][ns] = (f32x4){0.f, 0.f, 0.f, 0.f};
    float lsum[2][4] = {};

    // staging prefetch registers (this wave stages K chunks wave*4..+3 and
    // V chunks wave*4..+3; chunk = 1 KB, lane-linear)
    bf16x8 kpre[4], vpre[4];
    {
        const int j0 = koff;
        for (int t = 0; t < 4; t++) {
            int c = wave*4 + t;
            kpre[t] = *(const bf16x8*)(ksw +
                ((size_t)(b*256 + (j0 >> 4) + (c >> 3))*8 + (c & 7))*512 + lane*8);
            vpre[t] = *(const bf16x8*)(vsw +
                ((size_t)(b*128 + (j0 >> 5))*16 + c)*512 + lane*8);
        }
    }

    for (int jt = 0; jt < NT; jt++) {
        // commit staged tile to LDS (lane-linear: conflict-free)
        for (int t = 0; t < 4; t++) {
            *(bf16x8*)(ldsK + (wave*4 + t)*512 + lane*8) = kpre[t];
            *(bf16x8*)(ldsV + (wave*4 + t)*512 + lane*8) = vpre[t];
        }
        __syncthreads();

        // prefetch next tile (in flight during compute)
        if (jt + 1 < NT) {
            const int j0 = koff + (jt + 1)*32;
            for (int t = 0; t < 4; t++) {
                int c = wave*4 + t;
                kpre[t] = *(const bf16x8*)(ksw +
                    ((size_t)(b*256 + (j0 >> 4) + (c >> 3))*8 + (c & 7))*512 + lane*8);
                vpre[t] = *(const bf16x8*)(vsw +
                    ((size_t)(b*128 + (j0 >> 5))*16 + c)*512 + lane*8);
            }
        }

        // ---- S = Q K^T  (16 frag reads shared by both row-groups)
        f32x4 s[2][2];
        for (int g = 0; g < 2; g++)
            for (int jg = 0; jg < 2; jg++)
                s[g][jg] = (f32x4){0.f, 0.f, 0.f, 0.f};
        for (int jg = 0; jg < 2; jg++)
            for (int kk = 0; kk < 8; kk++) {
                bf16x8 kf = *(const bf16x8*)(ldsK + (jg*8 + kk)*512 + lane*8);
                s[0][jg] = __builtin_amdgcn_mfma_f32_16x16x32_bf16(qf[0][kk], kf, s[0][jg], 0, 0, 0);
                s[1][jg] = __builtin_amdgcn_mfma_f32_16x16x32_bf16(qf[1][kk], kf, s[1][jg], 0, 0, 0);
            }

        // ---- softmax-lite: p = exp(s), per-lane l partials, P -> wave LDS
        unsigned short* pw = ldsP[wave];
        for (int g = 0; g < 2; g++)
            for (int r = 0; r < 4; r++) {
                float p0 = __expf(s[g][0][r]);
                float p1 = __expf(s[g][1][r]);
                lsum[g][r] += p0 + p1;
                pw[(g*16 + quad*4 + r)*32 + lrow]      = f2bf(p0);
                pw[(g*16 + quad*4 + r)*32 + 16 + lrow] = f2bf(p1);
            }

        // P A-frags (same-wave LDS RAW: compiler inserts lgkmcnt wait)
        bf16x8 pa0 = *(const bf16x8*)(&pw[(lrow)*32      + quad*8]);
        bf16x8 pa1 = *(const bf16x8*)(&pw[(16 + lrow)*32 + quad*8]);

        // ---- PV (16 V-frag reads shared by both row-groups)
        for (int ns = 0; ns < 16; ns++) {
            bf16x8 vf = *(const bf16x8*)(ldsV + ns*512 + lane*8);
            o_acc[0][ns] = __builtin_amdgcn_mfma_f32_16x16x32_bf16(pa0, vf, o_acc[0][ns], 0, 0, 0);
            o_acc[1][ns] = __builtin_amdgcn_mfma_f32_16x16x32_bf16(pa1, vf, o_acc[1][ns], 0, 0, 0);
        }
        __syncthreads();
    }

    // reduce l over the 16 column-lanes (rows live on (quad, r))
    for (int g = 0; g < 2; g++)
        for (int r = 0; r < 4; r++) {
            float v = lsum[g][r];
            v += __shfl_xor(v, 1);
            v += __shfl_xor(v, 2);
            v += __shfl_xor(v, 4);
            v += __shfl_xor(v, 8);
            lsum[g][r] = v;
        }

    // store unnormalized O (fp32) + l
    float* ob = opart + ((size_t)(split*BB + b)*NN)*CC;
    for (int g = 0; g < 2; g++)
        for (int ns = 0; ns < 16; ns++)
            for (int r = 0; r < 4; r++) {
                int row = i0w + g*16 + quad*4 + r;
                ob[(size_t)row*CC + ns*16 + lrow] = o_acc[g][ns][r];
            }
    if (lrow == 0)
        for (int g = 0; g < 2; g++)
            for (int r = 0; r < 4; r++)
                lpart[(size_t)(split*BB + b)*NN + i0w + g*16 + quad*4 + r] = lsum[g][r];
}

// ---------------------------------------------------------------------------
// K4: proj (NT GEMM) + split-combine + bias + residual.
// B-operand = (o_part0[n][c] + o_part1[n][c]) / (l0[n] + l1[n])
// ---------------------------------------------------------------------------
__global__ __launch_bounds__(256) void proj_kernel(
    const float* __restrict__ opart, const float* __restrict__ lpart,
    const float* __restrict__ w_proj, const float* __restrict__ b_proj,
    const float* __restrict__ x, float* __restrict__ out)
{
    const int n0 = blockIdx.x * 64;
    const int o0 = blockIdx.y * 64;
    const int b  = blockIdx.z;
    const int tid = threadIdx.x;

    __shared__ float At[64][17];
    __shared__ float Bt[64][17];
    __shared__ float sinv[64];

    if (tid < 64) {
        size_t idx = (size_t)b*NN + n0 + tid;
        sinv[tid] = 1.0f / (lpart[idx] + lpart[(size_t)BB*NN + idx]);
    }
    __syncthreads();

    const float* p0 = opart;
    const float* p1 = opart + (size_t)BB*NN*CC;

    const int to = tid / 16, tn = tid % 16;
    float acc[4][4] = {};

    for (int c0 = 0; c0 < CC; c0 += 16) {
        int cl = tid % 16, rl = tid / 16;
        for (int r = 0; r < 4; r++)
            At[rl + r*16][cl] = w_proj[(size_t)(o0 + rl + r*16)*CC + c0 + cl];
        for (int r = 0; r < 4; r++) {
            int np = rl + r*16;
            size_t idx = ((size_t)b*NN + n0 + np)*CC + c0 + cl;
            Bt[np][cl] = (p0[idx] + p1[idx]) * sinv[np];
        }
        __syncthreads();
        for (int kk = 0; kk < 16; kk++) {
            float a[4], bb[4];
            for (int i = 0; i < 4; i++) a[i]  = At[to*4 + i][kk];
            for (int i = 0; i < 4; i++) bb[i] = Bt[tn*4 + i][kk];
            for (int i = 0; i < 4; i++)
                for (int j = 0; j < 4; j++)
                    acc[i][j] += a[i] * bb[j];
        }
        __syncthreads();
    }

    for (int i = 0; i < 4; i++) {
        int o = o0 + to*4 + i;
        float bias = b_proj[o];
        for (int j = 0; j < 4; j++) {
            int n = n0 + tn*4 + j;
            size_t idx = ((size_t)(b*CC + o))*NN + n;
            out[idx] = acc[i][j] + bias + x[idx];
        }
    }
}

// ---------------------------------------------------------------------------
extern "C" void kernel_launch(void* const* d_in, const int* in_sizes, int n_in,
                              void* d_out, int out_size, void* d_ws, size_t ws_size,
                              hipStream_t stream) {
    const float* x      = (const float*)d_in[0];
    const float* gamma  = (const float*)d_in[1];
    const float* beta   = (const float*)d_in[2];
    const float* w_qkv  = (const float*)d_in[3];
    const float* b_qkv  = (const float*)d_in[4];
    const float* w_proj = (const float*)d_in[5];
    const float* b_proj = (const float*)d_in[6];
    float* out = (float*)d_out;

    // workspace: q_sw | k_sw | v_sw (bf16, frag-order) | o_part[2] | l[2] | stats
    const size_t plane = (size_t)BB * NN * CC;   // 4,194,304 elems
    unsigned short* qsw = (unsigned short*)d_ws;
    unsigned short* ksw = qsw + plane;
    unsigned short* vsw = ksw + plane;
    float* opart = (float*)(vsw + plane);        // 2 * plane floats
    float* lpart = opart + 2*plane;              // 2 * BB*NN floats
    float* stats = lpart + 2*(size_t)BB*NN;

    gn_stats_kernel<<<BB*GG, 256, 0, stream>>>(x, stats);

    dim3 g2(NN/64, (3*CC)/64, BB);
    qkv_gemm_kernel<<<g2, 256, 0, stream>>>(x, gamma, beta, w_qkv, b_qkv,
                                            stats, qsw, ksw, vsw);

    attn_mfma_kernel<<<BB*32*NSPLIT, 256, 0, stream>>>(qsw, ksw, vsw, opart, lpart);

    dim3 g4(NN/64, CC/64, BB);
    proj_kernel<<<g4, 256, 0, stream>>>(opart, lpart, w_proj, b_proj, x, out);
}

// Round 4
// 252.396 us; speedup vs baseline: 19.6368x; 1.4477x over previous
//
#include <hip/hip_runtime.h>
#include <math.h>

// Problem constants: x [4, 256, 64, 64] fp32
#define BB   4
#define CC   256
#define NN   4096      // 64*64 spatial
#define GG   8
#define CPG  32        // channels per group
#define EPSV 1e-5f
#define SCALE 0.0625f  // 1/sqrt(256)
#define NSPLIT 2

typedef __attribute__((ext_vector_type(8))) short bf16x8;  // 8 bf16 = 4 VGPRs
typedef __attribute__((ext_vector_type(4))) float f32x4;

struct alignas(8) us4 { unsigned short x, y, z, w; };

static __device__ __forceinline__ unsigned short f2bf(float f) {
    union { float f; unsigned int u; } a; a.f = f;
    unsigned int r = a.u + 0x7fffu + ((a.u >> 16) & 1u);   // RNE
    return (unsigned short)(r >> 16);
}
static __device__ __forceinline__ float bf2f(short h) {
    union { unsigned int u; float f; } v;
    v.u = ((unsigned int)(unsigned short)h) << 16;
    return v.f;
}

// ---------------------------------------------------------------------------
// K0: weight fp32 -> bf16 (w_qkv 768x256 then w_proj 256x256, flat 262144)
// ---------------------------------------------------------------------------
__global__ __launch_bounds__(256) void wconv_kernel(
    const float* __restrict__ w_qkv, const float* __restrict__ w_proj,
    unsigned short* __restrict__ wbf)
{
    int idx = (blockIdx.x*256 + threadIdx.x) * 4;     // 0..262140
    float4 v;
    if (idx < 196608) v = *(const float4*)(w_qkv + idx);
    else              v = *(const float4*)(w_proj + (idx - 196608));
    us4 h = { f2bf(v.x), f2bf(v.y), f2bf(v.z), f2bf(v.w) };
    *(us4*)(wbf + idx) = h;
}

// ---------------------------------------------------------------------------
// K1a: GroupNorm partial stats. 256 blocks; block = (bg, slice of 8).
// ---------------------------------------------------------------------------
__global__ __launch_bounds__(256) void gn_stats1_kernel(const float* __restrict__ x,
                                                        float* __restrict__ partials) {
    const int bg = blockIdx.x >> 3, slice = blockIdx.x & 7;
    const float4* base = (const float4*)(x + (size_t)bg*CPG*NN + slice*16384);
    const int tid = threadIdx.x;
    float s = 0.f, sq = 0.f;
    for (int i = tid; i < 4096; i += 256) {
        float4 v = base[i];
        s  += v.x + v.y + v.z + v.w;
        sq += v.x*v.x + v.y*v.y + v.z*v.z + v.w*v.w;
    }
    __shared__ float ls[256], lq[256];
    ls[tid] = s; lq[tid] = sq;
    __syncthreads();
    for (int off = 128; off > 0; off >>= 1) {
        if (tid < off) { ls[tid] += ls[tid+off]; lq[tid] += lq[tid+off]; }
        __syncthreads();
    }
    if (tid == 0) { partials[blockIdx.x*2] = ls[0]; partials[blockIdx.x*2+1] = lq[0]; }
}

// K1b: finalize stats (32 groups)
__global__ __launch_bounds__(64) void gn_stats2_kernel(const float* __restrict__ partials,
                                                       float* __restrict__ stats) {
    int t = threadIdx.x;
    if (t < 32) {
        float s = 0.f, sq = 0.f;
        for (int i = 0; i < 8; i++) {
            s  += partials[(t*8 + i)*2];
            sq += partials[(t*8 + i)*2 + 1];
        }
        const float cnt = (float)(CPG*NN);
        float mean = s / cnt;
        float var  = sq / cnt - mean*mean;
        stats[t*2]   = mean;
        stats[t*2+1] = rsqrtf(var + EPSV);
    }
}

// ---------------------------------------------------------------------------
// K2: normalize + transpose: x [b][c][n] fp32 -> xnT [(b*4096+n)][256] bf16.
// 64c x 64n tiles via LDS. grid (64, 4, 4).
// ---------------------------------------------------------------------------
__global__ __launch_bounds__(256) void norm_t_kernel(
    const float* __restrict__ x, const float* __restrict__ gamma,
    const float* __restrict__ beta, const float* __restrict__ stats,
    unsigned short* __restrict__ xnT)
{
    const int n0 = blockIdx.x * 64;
    const int c0 = blockIdx.y * 64;
    const int b  = blockIdx.z;
    const int tid = threadIdx.x;
    __shared__ unsigned short T[64*68];
    __shared__ float ssc[64], ssh[64];
    if (tid < 64) {
        int c = c0 + tid;
        float mean = stats[(b*GG + (c>>5))*2];
        float rstd = stats[(b*GG + (c>>5))*2 + 1];
        float g = gamma[c], be = beta[c];
        ssc[tid] = rstd*g;
        ssh[tid] = be - mean*rstd*g;
    }
    __syncthreads();
    {
        int cl = tid >> 4, n4 = tid & 15;
        for (int i = 0; i < 4; i++) {
            int c = cl + i*16;
            float4 v = *(const float4*)(x + ((size_t)(b*CC + c0 + c))*NN + n0 + n4*4);
            float sc = ssc[c], sh = ssh[c];
            T[(n4*4+0)*68 + c] = f2bf(v.x*sc + sh);
            T[(n4*4+1)*68 + c] = f2bf(v.y*sc + sh);
            T[(n4*4+2)*68 + c] = f2bf(v.z*sc + sh);
            T[(n4*4+3)*68 + c] = f2bf(v.w*sc + sh);
        }
    }
    __syncthreads();
    {
        int nl = tid >> 3, cs = tid & 7;
        for (int i = 0; i < 2; i++) {
            int n = nl + i*32;
            *(bf16x8*)(xnT + ((size_t)(b*NN + n0 + n))*CC + c0 + cs*8) =
                *(const bf16x8*)&T[n*68 + cs*8];
        }
    }
}

// ---------------------------------------------------------------------------
// K3: QKV MFMA GEMM. C[n][o] = sum_c xnT[n][c]*W[o][c] (+bias), K=256.
// Block 256 = 4 waves, tile 128n x 64o. grid (128 R-tiles, 12 o-tiles).
// q/k blocks: D rows = o (A=W, B=xnT); v blocks: D rows = n (A=xnT, B=W)
// -> all epilogue LDS writes pack as us4. Outputs in attention frag-chunk
// layouts (identical formulas to R3):
//  q/k: off = ((b*256+(n>>4))*8 + oc>>5)*512 + (((oc>>3)&3)*16+(n&15))*8 + (oc&7)
//  v:   off = ((b*128+(n>>5))*16 + oc>>4)*512 + (((n>>3)&3)*16+(oc&15))*8 + (n&7)
// ---------------------------------------------------------------------------
__global__ __launch_bounds__(256) void qkv_mfma_kernel(
    const unsigned short* __restrict__ xnT, const unsigned short* __restrict__ wbf,
    const float* __restrict__ b_qkv,
    unsigned short* __restrict__ qsw, unsigned short* __restrict__ ksw,
    unsigned short* __restrict__ vsw)
{
    const int tid  = threadIdx.x;
    const int wave = tid >> 6, lane = tid & 63;
    const int lrow = lane & 15, quad = lane >> 4;
    const int R0   = blockIdx.x * 128;          // global row = b*4096 + n
    const int b    = blockIdx.x >> 5;
    const int nb0  = (blockIdx.x & 31) * 128;   // n within batch
    const int oBase = blockIdx.y * 64;          // 0..767
    const int which = oBase >> 8;               // 0:q 1:k 2:v
    const int o0l   = oBase & 255;
    const bool isV  = (which == 2);
    const int wn = wave >> 1, wo = wave & 1;

    const unsigned short* Abase;
    const unsigned short* Bbase;
    if (!isV) {
        Abase = wbf + ((size_t)(oBase + lrow))*CC + quad*8;
        Bbase = xnT + ((size_t)(R0 + wave*32 + lrow))*CC + quad*8;
    } else {
        Abase = xnT + ((size_t)(R0 + wn*64 + lrow))*CC + quad*8;
        Bbase = wbf + ((size_t)(oBase + wo*32 + lrow))*CC + quad*8;
    }

    f32x4 acc[4][2];
    for (int s = 0; s < 4; s++) for (int t = 0; t < 2; t++)
        acc[s][t] = (f32x4){0.f, 0.f, 0.f, 0.f};

    for (int c0 = 0; c0 < CC; c0 += 32) {
        bf16x8 af[4], bfr[2];
        for (int s = 0; s < 4; s++) af[s]  = *(const bf16x8*)(Abase + s*16*CC + c0);
        for (int t = 0; t < 2; t++) bfr[t] = *(const bf16x8*)(Bbase + t*16*CC + c0);
        for (int s = 0; s < 4; s++)
            for (int t = 0; t < 2; t++)
                acc[s][t] = __builtin_amdgcn_mfma_f32_16x16x32_bf16(af[s], bfr[t], acc[s][t], 0, 0, 0);
    }

    __shared__ unsigned short lds[8192];

    if (!isV) {
        const float sc = (which == 0) ? SCALE : 1.0f;
        for (int s = 0; s < 4; s++) {
            float bias[4];
            for (int r = 0; r < 4; r++) bias[r] = b_qkv[oBase + s*16 + quad*4 + r];
            for (int t = 0; t < 2; t++) {
                us4 h;
                h.x = f2bf((acc[s][t][0] + bias[0]) * sc);
                h.y = f2bf((acc[s][t][1] + bias[1]) * sc);
                h.z = f2bf((acc[s][t][2] + bias[2]) * sc);
                h.w = f2bf((acc[s][t][3] + bias[3]) * sc);
                int chunk = (wave*2 + t)*2 + (s>>1);
                int pos = (((s*2 + (quad>>1)) & 3)*16 + lrow)*8 + (quad&1)*4;
                *(us4*)&lds[chunk*512 + pos] = h;
            }
        }
    } else {
        for (int s = 0; s < 4; s++)
            for (int t = 0; t < 2; t++) {
                int oc = o0l + wo*32 + t*16 + lrow;
                float bias = b_qkv[512 + oc];
                us4 h;
                h.x = f2bf(acc[s][t][0] + bias);
                h.y = f2bf(acc[s][t][1] + bias);
                h.z = f2bf(acc[s][t][2] + bias);
                h.w = f2bf(acc[s][t][3] + bias);
                int chunk = (wn*2 + (s>>1))*4 + wo*2 + t;
                int pos = (((s&1)*2 + (quad>>1))*16 + lrow)*8 + (quad&1)*4;
                *(us4*)&lds[chunk*512 + pos] = h;
            }
    }
    __syncthreads();

    if (!isV) {
        unsigned short* dst = (which == 0) ? qsw : ksw;
        for (int it = 0; it < 4; it++) {
            int f = it*4 + (tid>>6);
            int ng_l = f >> 1, kk_l = f & 1;
            size_t off = ((size_t)(b*256 + (nb0>>4) + ng_l)*8 + (o0l>>5) + kk_l)*512 + lane*8;
            *(bf16x8*)(dst + off) = *(const bf16x8*)&lds[f*512 + lane*8];
        }
    } else {
        for (int it = 0; it < 4; it++) {
            int f = it*4 + (tid>>6);
            int jg_l = f >> 2, ns_l = f & 3;
            size_t off = ((size_t)(b*128 + (nb0>>5) + jg_l)*16 + (o0l>>4) + ns_l)*512 + lane*8;
            *(bf16x8*)(vsw + off) = *(const bf16x8*)&lds[f*512 + lane*8];
        }
    }
}

// ---------------------------------------------------------------------------
// K4: MFMA flash attention (unchanged core; opart now bf16).
// ---------------------------------------------------------------------------
__global__ __launch_bounds__(256, 1) void attn_mfma_kernel(
    const unsigned short* __restrict__ qsw, const unsigned short* __restrict__ ksw,
    const unsigned short* __restrict__ vsw,
    unsigned short* __restrict__ opart, float* __restrict__ lpart)
{
    const int tid  = threadIdx.x;
    const int wave = tid >> 6, lane = tid & 63;
    const int lrow = lane & 15, quad = lane >> 4;
    const int bx    = blockIdx.x;
    const int split = bx & 1;
    const int ig    = (bx >> 1) & 31;
    const int b     = bx >> 6;
    const int i0w   = ig*128 + wave*32;
    const int koff  = split * (NN / NSPLIT);
    const int NT    = (NN / NSPLIT) / 32;

    __shared__ unsigned short ldsK[16*512];
    __shared__ unsigned short ldsV[16*512];
    __shared__ unsigned short ldsP[4][1024];

    bf16x8 qf[2][8];
    for (int g = 0; g < 2; g++)
        for (int kk = 0; kk < 8; kk++)
            qf[g][kk] = *(const bf16x8*)(qsw +
                ((size_t)(b*256 + (i0w >> 4) + g)*8 + kk)*512 + lane*8);

    f32x4 o_acc[2][16];
    for (int g = 0; g < 2; g++)
        for (int ns = 0; ns < 16; ns++)
            o_acc[g][ns] = (f32x4){0.f, 0.f, 0.f, 0.f};
    float lsum[2][4] = {};

    bf16x8 kpre[4], vpre[4];
    {
        const int j0 = koff;
        for (int t = 0; t < 4; t++) {
            int c = wave*4 + t;
            kpre[t] = *(const bf16x8*)(ksw +
                ((size_t)(b*256 + (j0 >> 4) + (c >> 3))*8 + (c & 7))*512 + lane*8);
            vpre[t] = *(const bf16x8*)(vsw +
                ((size_t)(b*128 + (j0 >> 5))*16 + c)*512 + lane*8);
        }
    }

    for (int jt = 0; jt < NT; jt++) {
        for (int t = 0; t < 4; t++) {
            *(bf16x8*)(ldsK + (wave*4 + t)*512 + lane*8) = kpre[t];
            *(bf16x8*)(ldsV + (wave*4 + t)*512 + lane*8) = vpre[t];
        }
        __syncthreads();

        if (jt + 1 < NT) {
            const int j0 = koff + (jt + 1)*32;
            for (int t = 0; t < 4; t++) {
                int c = wave*4 + t;
                kpre[t] = *(const bf16x8*)(ksw +
                    ((size_t)(b*256 + (j0 >> 4) + (c >> 3))*8 + (c & 7))*512 + lane*8);
                vpre[t] = *(const bf16x8*)(vsw +
                    ((size_t)(b*128 + (j0 >> 5))*16 + c)*512 + lane*8);
            }
        }

        f32x4 s[2][2];
        for (int g = 0; g < 2; g++)
            for (int jg = 0; jg < 2; jg++)
                s[g][jg] = (f32x4){0.f, 0.f, 0.f, 0.f};
        for (int jg = 0; jg < 2; jg++)
            for (int kk = 0; kk < 8; kk++) {
                bf16x8 kf = *(const bf16x8*)(ldsK + (jg*8 + kk)*512 + lane*8);
                s[0][jg] = __builtin_amdgcn_mfma_f32_16x16x32_bf16(qf[0][kk], kf, s[0][jg], 0, 0, 0);
                s[1][jg] = __builtin_amdgcn_mfma_f32_16x16x32_bf16(qf[1][kk], kf, s[1][jg], 0, 0, 0);
            }

        unsigned short* pw = ldsP[wave];
        for (int g = 0; g < 2; g++)
            for (int r = 0; r < 4; r++) {
                float p0 = __expf(s[g][0][r]);
                float p1 = __expf(s[g][1][r]);
                lsum[g][r] += p0 + p1;
                pw[(g*16 + quad*4 + r)*32 + lrow]      = f2bf(p0);
                pw[(g*16 + quad*4 + r)*32 + 16 + lrow] = f2bf(p1);
            }

        bf16x8 pa0 = *(const bf16x8*)(&pw[(lrow)*32      + quad*8]);
        bf16x8 pa1 = *(const bf16x8*)(&pw[(16 + lrow)*32 + quad*8]);

        for (int ns = 0; ns < 16; ns++) {
            bf16x8 vf = *(const bf16x8*)(ldsV + ns*512 + lane*8);
            o_acc[0][ns] = __builtin_amdgcn_mfma_f32_16x16x32_bf16(pa0, vf, o_acc[0][ns], 0, 0, 0);
            o_acc[1][ns] = __builtin_amdgcn_mfma_f32_16x16x32_bf16(pa1, vf, o_acc[1][ns], 0, 0, 0);
        }
        __syncthreads();
    }

    for (int g = 0; g < 2; g++)
        for (int r = 0; r < 4; r++) {
            float v = lsum[g][r];
            v += __shfl_xor(v, 1);
            v += __shfl_xor(v, 2);
            v += __shfl_xor(v, 4);
            v += __shfl_xor(v, 8);
            lsum[g][r] = v;
        }

    unsigned short* ob = opart + ((size_t)(split*BB + b)*NN)*CC;
    for (int g = 0; g < 2; g++)
        for (int ns = 0; ns < 16; ns++)
            for (int r = 0; r < 4; r++) {
                int row = i0w + g*16 + quad*4 + r;
                ob[(size_t)row*CC + ns*16 + lrow] = f2bf(o_acc[g][ns][r]);
            }
    if (lrow == 0)
        for (int g = 0; g < 2; g++)
            for (int r = 0; r < 4; r++)
                lpart[(size_t)(split*BB + b)*NN + i0w + g*16 + quad*4 + r] = lsum[g][r];
}

// ---------------------------------------------------------------------------
// K5: proj MFMA + split-combine + bias + residual.
// A = bf16((opart0+opart1)*sinv) [n][c], B = w_proj bf16 [o][c], D rows = n.
// grid (128 R-tiles, 4 o-tiles).
// ---------------------------------------------------------------------------
__global__ __launch_bounds__(256) void proj_mfma_kernel(
    const unsigned short* __restrict__ opart, const float* __restrict__ lpart,
    const unsigned short* __restrict__ w2bf, const float* __restrict__ b_proj,
    const float* __restrict__ x, float* __restrict__ out)
{
    const int tid  = threadIdx.x;
    const int wave = tid >> 6, lane = tid & 63;
    const int lrow = lane & 15, quad = lane >> 4;
    const int R0   = blockIdx.x * 128;
    const int b    = blockIdx.x >> 5;
    const int nb0  = (blockIdx.x & 31) * 128;
    const int oBase = blockIdx.y * 64;
    const int wn = wave >> 1, wo = wave & 1;

    float sinv[4];
    for (int s = 0; s < 4; s++) {
        int n = nb0 + wn*64 + s*16 + lrow;
        float l0 = lpart[(size_t)b*NN + n];
        float l1 = lpart[(size_t)(BB + b)*NN + n];
        sinv[s] = 1.0f / (l0 + l1);
    }
    const unsigned short* A0 = opart + ((size_t)(R0 + wn*64 + lrow))*CC + quad*8;
    const unsigned short* A1 = A0 + (size_t)BB*NN*CC;
    const unsigned short* Bb = w2bf + ((size_t)(oBase + wo*32 + lrow))*CC + quad*8;

    f32x4 acc[4][2];
    for (int s = 0; s < 4; s++) for (int t = 0; t < 2; t++)
        acc[s][t] = (f32x4){0.f, 0.f, 0.f, 0.f};

    for (int c0 = 0; c0 < CC; c0 += 32) {
        bf16x8 af[4], bfr[2];
        for (int s = 0; s < 4; s++) {
            bf16x8 u0 = *(const bf16x8*)(A0 + s*16*CC + c0);
            bf16x8 u1 = *(const bf16x8*)(A1 + s*16*CC + c0);
            for (int e = 0; e < 8; e++)
                af[s][e] = (short)f2bf((bf2f(u0[e]) + bf2f(u1[e])) * sinv[s]);
        }
        for (int t = 0; t < 2; t++) bfr[t] = *(const bf16x8*)(Bb + t*16*CC + c0);
        for (int s = 0; s < 4; s++)
            for (int t = 0; t < 2; t++)
                acc[s][t] = __builtin_amdgcn_mfma_f32_16x16x32_bf16(af[s], bfr[t], acc[s][t], 0, 0, 0);
    }

    for (int s = 0; s < 4; s++)
        for (int t = 0; t < 2; t++) {
            int o = oBase + wo*32 + t*16 + lrow;
            int n = nb0 + wn*64 + s*16 + quad*4;
            size_t idx = ((size_t)(b*CC + o))*NN + n;
            float bias = b_proj[o];
            float4 xv = *(const float4*)(x + idx);
            float4 ov;
            ov.x = acc[s][t][0] + bias + xv.x;
            ov.y = acc[s][t][1] + bias + xv.y;
            ov.z = acc[s][t][2] + bias + xv.z;
            ov.w = acc[s][t][3] + bias + xv.w;
            *(float4*)(out + idx) = ov;
        }
}

// ---------------------------------------------------------------------------
extern "C" void kernel_launch(void* const* d_in, const int* in_sizes, int n_in,
                              void* d_out, int out_size, void* d_ws, size_t ws_size,
                              hipStream_t stream) {
    const float* x      = (const float*)d_in[0];
    const float* gamma  = (const float*)d_in[1];
    const float* beta   = (const float*)d_in[2];
    const float* w_qkv  = (const float*)d_in[3];
    const float* b_qkv  = (const float*)d_in[4];
    const float* w_proj = (const float*)d_in[5];
    const float* b_proj = (const float*)d_in[6];
    float* out = (float*)d_out;

    const size_t plane = (size_t)BB * NN * CC;     // 4,194,304 elems
    unsigned short* xnT = (unsigned short*)d_ws;
    unsigned short* qsw = xnT + plane;
    unsigned short* ksw = qsw + plane;
    unsigned short* vsw = ksw + plane;
    unsigned short* wbf = vsw + plane;             // 262144 us
    unsigned short* opart = wbf + 262144;          // 2*plane us (bf16)
    float* lpart    = (float*)(opart + 2*plane);   // 2*BB*NN floats
    float* partials = lpart + 2*(size_t)BB*NN;     // 512 floats
    float* stats    = partials + 512;              // 64 floats

    wconv_kernel<<<256, 256, 0, stream>>>(w_qkv, w_proj, wbf);
    gn_stats1_kernel<<<256, 256, 0, stream>>>(x, partials);
    gn_stats2_kernel<<<1, 64, 0, stream>>>(partials, stats);

    dim3 gnt(64, 4, BB);
    norm_t_kernel<<<gnt, 256, 0, stream>>>(x, gamma, beta, stats, xnT);

    dim3 gq(128, 12);
    qkv_mfma_kernel<<<gq, 256, 0, stream>>>(xnT, wbf, b_qkv, qsw, ksw, vsw);

    attn_mfma_kernel<<<BB*32*NSPLIT, 256, 0, stream>>>(qsw, ksw, vsw, opart, lpart);

    dim3 gp(128, 4);
    proj_mfma_kernel<<<gp, 256, 0, stream>>>(opart, lpart, wbf + 196608, b_proj, x, out);
}

// Round 5
// 240.662 us; speedup vs baseline: 20.5943x; 1.0488x over previous
//
#include <hip/hip_runtime.h>
#include <math.h>

// Problem constants: x [4, 256, 64, 64] fp32
#define BB   4
#define CC   256
#define NN   4096      // 64*64 spatial
#define GG   8
#define CPG  32        // channels per group
#define EPSV 1e-5f
#define SCALE 0.0625f  // 1/sqrt(256)
#define NSPLIT 4

typedef __attribute__((ext_vector_type(8))) short bf16x8;  // 8 bf16 = 4 VGPRs
typedef __attribute__((ext_vector_type(4))) short bf16x4;  // 8 B, align 8
typedef __attribute__((ext_vector_type(4))) float f32x4;

struct alignas(8) us4 { unsigned short x, y, z, w; };

static __device__ __forceinline__ unsigned short f2bf(float f) {
    union { float f; unsigned int u; } a; a.f = f;
    unsigned int r = a.u + 0x7fffu + ((a.u >> 16) & 1u);   // RNE
    return (unsigned short)(r >> 16);
}
static __device__ __forceinline__ float bf2f(short h) {
    union { unsigned int u; float f; } v;
    v.u = ((unsigned int)(unsigned short)h) << 16;
    return v.f;
}

// ---------------------------------------------------------------------------
// K0: weight fp32 -> bf16 (w_qkv 768x256 then w_proj 256x256, flat 262144)
// ---------------------------------------------------------------------------
__global__ __launch_bounds__(256) void wconv_kernel(
    const float* __restrict__ w_qkv, const float* __restrict__ w_proj,
    unsigned short* __restrict__ wbf)
{
    int idx = (blockIdx.x*256 + threadIdx.x) * 4;     // 0..262140
    float4 v;
    if (idx < 196608) v = *(const float4*)(w_qkv + idx);
    else              v = *(const float4*)(w_proj + (idx - 196608));
    us4 h = { f2bf(v.x), f2bf(v.y), f2bf(v.z), f2bf(v.w) };
    *(us4*)(wbf + idx) = h;
}

// ---------------------------------------------------------------------------
// K1a: GroupNorm partial stats. 256 blocks; block = (bg, slice of 8).
// ---------------------------------------------------------------------------
__global__ __launch_bounds__(256) void gn_stats1_kernel(const float* __restrict__ x,
                                                        float* __restrict__ partials) {
    const int bg = blockIdx.x >> 3, slice = blockIdx.x & 7;
    const float4* base = (const float4*)(x + (size_t)bg*CPG*NN + slice*16384);
    const int tid = threadIdx.x;
    float s = 0.f, sq = 0.f;
    for (int i = tid; i < 4096; i += 256) {
        float4 v = base[i];
        s  += v.x + v.y + v.z + v.w;
        sq += v.x*v.x + v.y*v.y + v.z*v.z + v.w*v.w;
    }
    __shared__ float ls[256], lq[256];
    ls[tid] = s; lq[tid] = sq;
    __syncthreads();
    for (int off = 128; off > 0; off >>= 1) {
        if (tid < off) { ls[tid] += ls[tid+off]; lq[tid] += lq[tid+off]; }
        __syncthreads();
    }
    if (tid == 0) { partials[blockIdx.x*2] = ls[0]; partials[blockIdx.x*2+1] = lq[0]; }
}

// K1b: finalize stats (32 groups)
__global__ __launch_bounds__(64) void gn_stats2_kernel(const float* __restrict__ partials,
                                                       float* __restrict__ stats) {
    int t = threadIdx.x;
    if (t < 32) {
        float s = 0.f, sq = 0.f;
        for (int i = 0; i < 8; i++) {
            s  += partials[(t*8 + i)*2];
            sq += partials[(t*8 + i)*2 + 1];
        }
        const float cnt = (float)(CPG*NN);
        float mean = s / cnt;
        float var  = sq / cnt - mean*mean;
        stats[t*2]   = mean;
        stats[t*2+1] = rsqrtf(var + EPSV);
    }
}

// ---------------------------------------------------------------------------
// K2: normalize + transpose: x [b][c][n] fp32 -> xnT [(b*4096+n)][256] bf16.
// ---------------------------------------------------------------------------
__global__ __launch_bounds__(256) void norm_t_kernel(
    const float* __restrict__ x, const float* __restrict__ gamma,
    const float* __restrict__ beta, const float* __restrict__ stats,
    unsigned short* __restrict__ xnT)
{
    const int n0 = blockIdx.x * 64;
    const int c0 = blockIdx.y * 64;
    const int b  = blockIdx.z;
    const int tid = threadIdx.x;
    __shared__ unsigned short T[64*68];
    __shared__ float ssc[64], ssh[64];
    if (tid < 64) {
        int c = c0 + tid;
        float mean = stats[(b*GG + (c>>5))*2];
        float rstd = stats[(b*GG + (c>>5))*2 + 1];
        float g = gamma[c], be = beta[c];
        ssc[tid] = rstd*g;
        ssh[tid] = be - mean*rstd*g;
    }
    __syncthreads();
    {
        int cl = tid >> 4, n4 = tid & 15;
        for (int i = 0; i < 4; i++) {
            int c = cl + i*16;
            float4 v = *(const float4*)(x + ((size_t)(b*CC + c0 + c))*NN + n0 + n4*4);
            float sc = ssc[c], sh = ssh[c];
            T[(n4*4+0)*68 + c] = f2bf(v.x*sc + sh);
            T[(n4*4+1)*68 + c] = f2bf(v.y*sc + sh);
            T[(n4*4+2)*68 + c] = f2bf(v.z*sc + sh);
            T[(n4*4+3)*68 + c] = f2bf(v.w*sc + sh);
        }
    }
    __syncthreads();
    {
        int nl = tid >> 3, cs = tid & 7;
        for (int i = 0; i < 2; i++) {
            int n = nl + i*32;
            *(bf16x8*)(xnT + ((size_t)(b*NN + n0 + n))*CC + c0 + cs*8) =
                *(const bf16x8*)&T[n*68 + cs*8];
        }
    }
}

// ---------------------------------------------------------------------------
// K3: QKV MFMA GEMM -> q/k/v in attention frag-chunk layouts (same as R4).
// ---------------------------------------------------------------------------
__global__ __launch_bounds__(256) void qkv_mfma_kernel(
    const unsigned short* __restrict__ xnT, const unsigned short* __restrict__ wbf,
    const float* __restrict__ b_qkv,
    unsigned short* __restrict__ qsw, unsigned short* __restrict__ ksw,
    unsigned short* __restrict__ vsw)
{
    const int tid  = threadIdx.x;
    const int wave = tid >> 6, lane = tid & 63;
    const int lrow = lane & 15, quad = lane >> 4;
    const int R0   = blockIdx.x * 128;
    const int b    = blockIdx.x >> 5;
    const int nb0  = (blockIdx.x & 31) * 128;
    const int oBase = blockIdx.y * 64;
    const int which = oBase >> 8;
    const int o0l   = oBase & 255;
    const bool isV  = (which == 2);
    const int wn = wave >> 1, wo = wave & 1;

    const unsigned short* Abase;
    const unsigned short* Bbase;
    if (!isV) {
        Abase = wbf + ((size_t)(oBase + lrow))*CC + quad*8;
        Bbase = xnT + ((size_t)(R0 + wave*32 + lrow))*CC + quad*8;
    } else {
        Abase = xnT + ((size_t)(R0 + wn*64 + lrow))*CC + quad*8;
        Bbase = wbf + ((size_t)(oBase + wo*32 + lrow))*CC + quad*8;
    }

    f32x4 acc[4][2];
    for (int s = 0; s < 4; s++) for (int t = 0; t < 2; t++)
        acc[s][t] = (f32x4){0.f, 0.f, 0.f, 0.f};

    for (int c0 = 0; c0 < CC; c0 += 32) {
        bf16x8 af[4], bfr[2];
        for (int s = 0; s < 4; s++) af[s]  = *(const bf16x8*)(Abase + s*16*CC + c0);
        for (int t = 0; t < 2; t++) bfr[t] = *(const bf16x8*)(Bbase + t*16*CC + c0);
        for (int s = 0; s < 4; s++)
            for (int t = 0; t < 2; t++)
                acc[s][t] = __builtin_amdgcn_mfma_f32_16x16x32_bf16(af[s], bfr[t], acc[s][t], 0, 0, 0);
    }

    __shared__ unsigned short lds[8192];

    if (!isV) {
        const float sc = (which == 0) ? SCALE : 1.0f;
        for (int s = 0; s < 4; s++) {
            float bias[4];
            for (int r = 0; r < 4; r++) bias[r] = b_qkv[oBase + s*16 + quad*4 + r];
            for (int t = 0; t < 2; t++) {
                us4 h;
                h.x = f2bf((acc[s][t][0] + bias[0]) * sc);
                h.y = f2bf((acc[s][t][1] + bias[1]) * sc);
                h.z = f2bf((acc[s][t][2] + bias[2]) * sc);
                h.w = f2bf((acc[s][t][3] + bias[3]) * sc);
                int chunk = (wave*2 + t)*2 + (s>>1);
                int pos = (((s*2 + (quad>>1)) & 3)*16 + lrow)*8 + (quad&1)*4;
                *(us4*)&lds[chunk*512 + pos] = h;
            }
        }
    } else {
        for (int s = 0; s < 4; s++)
            for (int t = 0; t < 2; t++) {
                int oc = o0l + wo*32 + t*16 + lrow;
                float bias = b_qkv[512 + oc];
                us4 h;
                h.x = f2bf(acc[s][t][0] + bias);
                h.y = f2bf(acc[s][t][1] + bias);
                h.z = f2bf(acc[s][t][2] + bias);
                h.w = f2bf(acc[s][t][3] + bias);
                int chunk = (wn*2 + (s>>1))*4 + wo*2 + t;
                int pos = (((s&1)*2 + (quad>>1))*16 + lrow)*8 + (quad&1)*4;
                *(us4*)&lds[chunk*512 + pos] = h;
            }
    }
    __syncthreads();

    if (!isV) {
        unsigned short* dst = (which == 0) ? qsw : ksw;
        for (int it = 0; it < 4; it++) {
            int f = it*4 + (tid>>6);
            int ng_l = f >> 1, kk_l = f & 1;
            size_t off = ((size_t)(b*256 + (nb0>>4) + ng_l)*8 + (o0l>>5) + kk_l)*512 + lane*8;
            *(bf16x8*)(dst + off) = *(const bf16x8*)&lds[f*512 + lane*8];
        }
    } else {
        for (int it = 0; it < 4; it++) {
            int f = it*4 + (tid>>6);
            int jg_l = f >> 2, ns_l = f & 3;
            size_t off = ((size_t)(b*128 + (nb0>>5) + jg_l)*16 + (o0l>>4) + ns_l)*512 + lane*8;
            *(bf16x8*)(vsw + off) = *(const bf16x8*)&lds[f*512 + lane*8];
        }
    }
}

// ---------------------------------------------------------------------------
// K4: MFMA flash attention. NSPLIT=4 -> grid 512 (2 blocks/CU).
// Conflict-free ldsP (stride 36 us), pointer-stride prefetch, frag-chunk
// epilogue (LDS bounce -> coalesced b128 stores).
// opart chunk layout, plane per (split,b): chunk(rg, kk) = rg*8+kk, 512 us;
//   element O[rg*16+m][kk*32+q2*8+e] at pos (q2*16+m)*8+e.
// ---------------------------------------------------------------------------
__global__ __launch_bounds__(256, 2) void attn_mfma_kernel(
    const unsigned short* __restrict__ qsw, const unsigned short* __restrict__ ksw,
    const unsigned short* __restrict__ vsw,
    unsigned short* __restrict__ opart, float* __restrict__ lpart)
{
    const int tid  = threadIdx.x;
    const int wave = tid >> 6, lane = tid & 63;
    const int lrow = lane & 15, quad = lane >> 4;
    const int bx    = blockIdx.x;
    const int split = bx & 3;
    const int ig    = (bx >> 2) & 31;
    const int b     = bx >> 7;
    const int i0w   = ig*128 + wave*32;
    const int koff  = split * (NN / NSPLIT);   // 0,1024,2048,3072
    const int NT    = (NN / NSPLIT) / 32;      // 32 tiles

    __shared__ unsigned short ldsKV[16384];    // K chunks [0,8192), V [8192,16384)
    __shared__ unsigned short ldsP[4][32*36];  // stride 36 us: conflict-free

    unsigned short* ldsK = ldsKV;
    unsigned short* ldsV = ldsKV + 8192;

    // Q A-frags
    bf16x8 qf[2][8];
    {
        const unsigned short* qb = qsw + ((size_t)b << 20) + (size_t)i0w*256 + lane*8;
        for (int g = 0; g < 2; g++)
            for (int kk = 0; kk < 8; kk++)
                qf[g][kk] = *(const bf16x8*)(qb + g*4096 + kk*512);
    }

    f32x4 o_acc[2][16];
    for (int g = 0; g < 2; g++)
        for (int ns = 0; ns < 16; ns++)
            o_acc[g][ns] = (f32x4){0.f, 0.f, 0.f, 0.f};
    float lsum[2][4] = {};

    // pointer-stride prefetch: chunk addr = base + j0*256 + c*512 (+8192/tile)
    const unsigned short* kp = ksw + ((size_t)b << 20) + (size_t)koff*256 + wave*2048 + lane*8;
    const unsigned short* vp = vsw + ((size_t)b << 20) + (size_t)koff*256 + wave*2048 + lane*8;

    bf16x8 kpre[4], vpre[4];
    for (int t = 0; t < 4; t++) {
        kpre[t] = *(const bf16x8*)(kp + t*512);
        vpre[t] = *(const bf16x8*)(vp + t*512);
    }
    kp += 8192; vp += 8192;

    for (int jt = 0; jt < NT; jt++) {
        for (int t = 0; t < 4; t++) {
            *(bf16x8*)(ldsK + wave*2048 + t*512 + lane*8) = kpre[t];
            *(bf16x8*)(ldsV + wave*2048 + t*512 + lane*8) = vpre[t];
        }
        __syncthreads();

        if (jt + 1 < NT) {
            for (int t = 0; t < 4; t++) {
                kpre[t] = *(const bf16x8*)(kp + t*512);
                vpre[t] = *(const bf16x8*)(vp + t*512);
            }
            kp += 8192; vp += 8192;
        }

        // ---- S = Q K^T
        f32x4 s[2][2];
        for (int g = 0; g < 2; g++)
            for (int jg = 0; jg < 2; jg++)
                s[g][jg] = (f32x4){0.f, 0.f, 0.f, 0.f};
        for (int jg = 0; jg < 2; jg++)
            for (int kk = 0; kk < 8; kk++) {
                bf16x8 kf = *(const bf16x8*)(ldsK + (jg*8 + kk)*512 + lane*8);
                s[0][jg] = __builtin_amdgcn_mfma_f32_16x16x32_bf16(qf[0][kk], kf, s[0][jg], 0, 0, 0);
                s[1][jg] = __builtin_amdgcn_mfma_f32_16x16x32_bf16(qf[1][kk], kf, s[1][jg], 0, 0, 0);
            }

        // ---- p = exp(s); per-lane l partials; P -> per-wave LDS (stride 36)
        unsigned short* pw = ldsP[wave];
        for (int g = 0; g < 2; g++)
            for (int r = 0; r < 4; r++) {
                float p0 = __expf(s[g][0][r]);
                float p1 = __expf(s[g][1][r]);
                lsum[g][r] += p0 + p1;
                pw[(g*16 + quad*4 + r)*36 + lrow]      = f2bf(p0);
                pw[(g*16 + quad*4 + r)*36 + 16 + lrow] = f2bf(p1);
            }

        // P A-frags: 2x 8B reads (rows are 72 B apart -> 8B aligned)
        bf16x8 pa[2];
        for (int g = 0; g < 2; g++) {
            int idx = (g*16 + lrow)*36 + quad*8;
            bf16x4 lo = *(const bf16x4*)(pw + idx);
            bf16x4 hi = *(const bf16x4*)(pw + idx + 4);
            pa[g] = __builtin_shufflevector(lo, hi, 0, 1, 2, 3, 4, 5, 6, 7);
        }

        // ---- PV
        for (int ns = 0; ns < 16; ns++) {
            bf16x8 vf = *(const bf16x8*)(ldsV + ns*512 + lane*8);
            o_acc[0][ns] = __builtin_amdgcn_mfma_f32_16x16x32_bf16(pa[0], vf, o_acc[0][ns], 0, 0, 0);
            o_acc[1][ns] = __builtin_amdgcn_mfma_f32_16x16x32_bf16(pa[1], vf, o_acc[1][ns], 0, 0, 0);
        }
        __syncthreads();
    }

    // reduce l over the 16 column-lanes
    for (int g = 0; g < 2; g++)
        for (int r = 0; r < 4; r++) {
            float v = lsum[g][r];
            v += __shfl_xor(v, 1);
            v += __shfl_xor(v, 2);
            v += __shfl_xor(v, 4);
            v += __shfl_xor(v, 8);
            lsum[g][r] = v;
        }

    // epilogue: bounce O through LDS into frag-chunk layout, store b128.
    // (safe: after final barrier; each wave uses its private 4096-us region)
    unsigned short* reg = ldsKV + wave*4096;
    const size_t planeb = ((size_t)(split*BB + b)) << 20;
    for (int g = 0; g < 2; g++) {
        for (int ns = 0; ns < 16; ns++) {
            int kk = ns >> 1;
            int posbase = ((ns & 1)*2 + (lrow >> 3))*128 + (lrow & 7) + quad*32;
            for (int r = 0; r < 4; r++)
                reg[kk*512 + posbase + r*8] = f2bf(o_acc[g][ns][r]);
        }
        unsigned short* dst = opart + planeb + ((size_t)((i0w >> 4) + g))*4096;
        for (int kk = 0; kk < 8; kk++)
            *(bf16x8*)(dst + kk*512 + lane*8) = *(const bf16x8*)(reg + kk*512 + lane*8);
    }
    if (lrow == 0)
        for (int g = 0; g < 2; g++)
            for (int r = 0; r < 4; r++)
                lpart[(size_t)(split*BB + b)*NN + i0w + g*16 + quad*4 + r] = lsum[g][r];
}

// ---------------------------------------------------------------------------
// K5: proj MFMA + 4-way split-combine + bias + residual.
// A-frags read lane-linear from opart chunk layout (4 planes summed, *1/l).
// ---------------------------------------------------------------------------
__global__ __launch_bounds__(256) void proj_mfma_kernel(
    const unsigned short* __restrict__ opart, const float* __restrict__ lpart,
    const unsigned short* __restrict__ w2bf, const float* __restrict__ b_proj,
    const float* __restrict__ x, float* __restrict__ out)
{
    const int tid  = threadIdx.x;
    const int wave = tid >> 6, lane = tid & 63;
    const int lrow = lane & 15, quad = lane >> 4;
    const int b    = blockIdx.x >> 5;
    const int nb0  = (blockIdx.x & 31) * 128;
    const int oBase = blockIdx.y * 64;
    const int wn = wave >> 1, wo = wave & 1;

    float sinv[4];
    for (int s = 0; s < 4; s++) {
        int n = nb0 + wn*64 + s*16 + lrow;
        float l = 0.f;
        for (int sp = 0; sp < NSPLIT; sp++)
            l += lpart[(size_t)(sp*BB + b)*NN + n];
        sinv[s] = 1.0f / l;
    }

    const int rgl = (nb0 >> 4) + wn*4;     // rowgroup (rel. to batch) for s=0
    const unsigned short* Bb = w2bf + ((size_t)(oBase + wo*32 + lrow))*CC + quad*8;

    f32x4 acc[4][2];
    for (int s = 0; s < 4; s++) for (int t = 0; t < 2; t++)
        acc[s][t] = (f32x4){0.f, 0.f, 0.f, 0.f};

    const size_t pstride = (size_t)BB << 20;   // plane-to-plane (us)
    const unsigned short* Ab = opart + ((size_t)b << 20) + (size_t)rgl*4096 + lane*8;

    for (int c0 = 0; c0 < CC; c0 += 32) {
        const int kk = c0 >> 5;
        bf16x8 af[4], bfr[2];
        for (int s = 0; s < 4; s++) {
            const unsigned short* a0 = Ab + (size_t)s*4096 + kk*512;
            bf16x8 u0 = *(const bf16x8*)(a0);
            bf16x8 u1 = *(const bf16x8*)(a0 + pstride);
            bf16x8 u2 = *(const bf16x8*)(a0 + 2*pstride);
            bf16x8 u3 = *(const bf16x8*)(a0 + 3*pstride);
            for (int e = 0; e < 8; e++)
                af[s][e] = (short)f2bf((bf2f(u0[e]) + bf2f(u1[e]) + bf2f(u2[e]) + bf2f(u3[e])) * sinv[s]);
        }
        for (int t = 0; t < 2; t++) bfr[t] = *(const bf16x8*)(Bb + t*16*CC + c0);
        for (int s = 0; s < 4; s++)
            for (int t = 0; t < 2; t++)
                acc[s][t] = __builtin_amdgcn_mfma_f32_16x16x32_bf16(af[s], bfr[t], acc[s][t], 0, 0, 0);
    }

    for (int s = 0; s < 4; s++)
        for (int t = 0; t < 2; t++) {
            int o = oBase + wo*32 + t*16 + lrow;
            int n = nb0 + wn*64 + s*16 + quad*4;
            size_t idx = ((size_t)(b*CC + o))*NN + n;
            float bias = b_proj[o];
            float4 xv = *(const float4*)(x + idx);
            float4 ov;
            ov.x = acc[s][t][0] + bias + xv.x;
            ov.y = acc[s][t][1] + bias + xv.y;
            ov.z = acc[s][t][2] + bias + xv.z;
            ov.w = acc[s][t][3] + bias + xv.w;
            *(float4*)(out + idx) = ov;
        }
}

// ---------------------------------------------------------------------------
extern "C" void kernel_launch(void* const* d_in, const int* in_sizes, int n_in,
                              void* d_out, int out_size, void* d_ws, size_t ws_size,
                              hipStream_t stream) {
    const float* x      = (const float*)d_in[0];
    const float* gamma  = (const float*)d_in[1];
    const float* beta   = (const float*)d_in[2];
    const float* w_qkv  = (const float*)d_in[3];
    const float* b_qkv  = (const float*)d_in[4];
    const float* w_proj = (const float*)d_in[5];
    const float* b_proj = (const float*)d_in[6];
    float* out = (float*)d_out;

    const size_t plane = (size_t)BB * NN * CC;     // 4,194,304 elems
    unsigned short* xnT = (unsigned short*)d_ws;
    unsigned short* qsw = xnT + plane;
    unsigned short* ksw = qsw + plane;
    unsigned short* vsw = ksw + plane;
    unsigned short* wbf = vsw + plane;             // 262144 us
    unsigned short* opart = wbf + 262144;          // NSPLIT*plane us (bf16)
    float* lpart    = (float*)(opart + (size_t)NSPLIT*plane);  // NSPLIT*BB*NN
    float* partials = lpart + (size_t)NSPLIT*BB*NN;
    float* stats    = partials + 512;

    wconv_kernel<<<256, 256, 0, stream>>>(w_qkv, w_proj, wbf);
    gn_stats1_kernel<<<256, 256, 0, stream>>>(x, partials);
    gn_stats2_kernel<<<1, 64, 0, stream>>>(partials, stats);

    dim3 gnt(64, 4, BB);
    norm_t_kernel<<<gnt, 256, 0, stream>>>(x, gamma, beta, stats, xnT);

    dim3 gq(128, 12);
    qkv_mfma_kernel<<<gq, 256, 0, stream>>>(xnT, wbf, b_qkv, qsw, ksw, vsw);

    attn_mfma_kernel<<<BB*32*NSPLIT, 256, 0, stream>>>(qsw, ksw, vsw, opart, lpart);

    dim3 gp(128, 4);
    proj_mfma_kernel<<<gp, 256, 0, stream>>>(opart, lpart, wbf + 196608, b_proj, x, out);
}

// Round 6
// 232.430 us; speedup vs baseline: 21.3237x; 1.0354x over previous
//
#include <hip/hip_runtime.h>
#include <math.h>

// Problem constants: x [4, 256, 64, 64] fp32
#define BB   4
#define CC   256
#define NN   4096      // 64*64 spatial
#define GG   8
#define CPG  32        // channels per group
#define EPSV 1e-5f
#define SCALE 0.0625f  // 1/sqrt(256)
#define NSPLIT 4
#define PSTR 40        // ldsP row stride in ushorts (80 B: 16B-aligned rows)

typedef __attribute__((ext_vector_type(8))) short bf16x8;  // 8 bf16 = 4 VGPRs
typedef __attribute__((ext_vector_type(4))) float f32x4;

struct alignas(8) us4 { unsigned short x, y, z, w; };

static __device__ __forceinline__ unsigned short f2bf(float f) {
    union { float f; unsigned int u; } a; a.f = f;
    unsigned int r = a.u + 0x7fffu + ((a.u >> 16) & 1u);   // RNE
    return (unsigned short)(r >> 16);
}
static __device__ __forceinline__ float bf2f(short h) {
    union { unsigned int u; float f; } v;
    v.u = ((unsigned int)(unsigned short)h) << 16;
    return v.f;
}
// async global->LDS, 16B/lane: per-lane gptr, wave-uniform LDS base (+lane*16 by HW)
static __device__ __forceinline__ void async16(const unsigned short* g, unsigned short* l) {
    __builtin_amdgcn_global_load_lds(
        (const __attribute__((address_space(1))) unsigned int*)g,
        (__attribute__((address_space(3))) unsigned int*)l,
        16, 0, 0);
}

// ---------------------------------------------------------------------------
// K0: merged prep: blocks 0..255 = GroupNorm partial stats; 256..511 = weight
// fp32->bf16 conversion (w_qkv 768x256 then w_proj 256x256).
// ---------------------------------------------------------------------------
__global__ __launch_bounds__(256) void prep_kernel(
    const float* __restrict__ x, const float* __restrict__ w_qkv,
    const float* __restrict__ w_proj, float* __restrict__ partials,
    unsigned short* __restrict__ wbf)
{
    const int tid = threadIdx.x;
    if (blockIdx.x >= 256) {
        int idx = ((blockIdx.x - 256)*256 + tid) * 4;     // 0..262140
        float4 v;
        if (idx < 196608) v = *(const float4*)(w_qkv + idx);
        else              v = *(const float4*)(w_proj + (idx - 196608));
        us4 h = { f2bf(v.x), f2bf(v.y), f2bf(v.z), f2bf(v.w) };
        *(us4*)(wbf + idx) = h;
        return;
    }
    const int bg = blockIdx.x >> 3, slice = blockIdx.x & 7;
    const float4* base = (const float4*)(x + (size_t)bg*CPG*NN + slice*16384);
    float s = 0.f, sq = 0.f;
    for (int i = tid; i < 4096; i += 256) {
        float4 v = base[i];
        s  += v.x + v.y + v.z + v.w;
        sq += v.x*v.x + v.y*v.y + v.z*v.z + v.w*v.w;
    }
    __shared__ float ls[256], lq[256];
    ls[tid] = s; lq[tid] = sq;
    __syncthreads();
    for (int off = 128; off > 0; off >>= 1) {
        if (tid < off) { ls[tid] += ls[tid+off]; lq[tid] += lq[tid+off]; }
        __syncthreads();
    }
    if (tid == 0) { partials[blockIdx.x*2] = ls[0]; partials[blockIdx.x*2+1] = lq[0]; }
}

// K1b: finalize stats (32 groups)
__global__ __launch_bounds__(64) void gn_stats2_kernel(const float* __restrict__ partials,
                                                       float* __restrict__ stats) {
    int t = threadIdx.x;
    if (t < 32) {
        float s = 0.f, sq = 0.f;
        for (int i = 0; i < 8; i++) {
            s  += partials[(t*8 + i)*2];
            sq += partials[(t*8 + i)*2 + 1];
        }
        const float cnt = (float)(CPG*NN);
        float mean = s / cnt;
        float var  = sq / cnt - mean*mean;
        stats[t*2]   = mean;
        stats[t*2+1] = rsqrtf(var + EPSV);
    }
}

// ---------------------------------------------------------------------------
// K2: normalize + transpose: x [b][c][n] fp32 -> xnT [(b*4096+n)][256] bf16.
// ---------------------------------------------------------------------------
__global__ __launch_bounds__(256) void norm_t_kernel(
    const float* __restrict__ x, const float* __restrict__ gamma,
    const float* __restrict__ beta, const float* __restrict__ stats,
    unsigned short* __restrict__ xnT)
{
    const int n0 = blockIdx.x * 64;
    const int c0 = blockIdx.y * 64;
    const int b  = blockIdx.z;
    const int tid = threadIdx.x;
    __shared__ unsigned short T[64*68];
    __shared__ float ssc[64], ssh[64];
    if (tid < 64) {
        int c = c0 + tid;
        float mean = stats[(b*GG + (c>>5))*2];
        float rstd = stats[(b*GG + (c>>5))*2 + 1];
        float g = gamma[c], be = beta[c];
        ssc[tid] = rstd*g;
        ssh[tid] = be - mean*rstd*g;
    }
    __syncthreads();
    {
        int cl = tid >> 4, n4 = tid & 15;
        for (int i = 0; i < 4; i++) {
            int c = cl + i*16;
            float4 v = *(const float4*)(x + ((size_t)(b*CC + c0 + c))*NN + n0 + n4*4);
            float sc = ssc[c], sh = ssh[c];
            T[(n4*4+0)*68 + c] = f2bf(v.x*sc + sh);
            T[(n4*4+1)*68 + c] = f2bf(v.y*sc + sh);
            T[(n4*4+2)*68 + c] = f2bf(v.z*sc + sh);
            T[(n4*4+3)*68 + c] = f2bf(v.w*sc + sh);
        }
    }
    __syncthreads();
    {
        int nl = tid >> 3, cs = tid & 7;
        for (int i = 0; i < 2; i++) {
            int n = nl + i*32;
            *(bf16x8*)(xnT + ((size_t)(b*NN + n0 + n))*CC + c0 + cs*8) =
                *(const bf16x8*)&T[n*68 + cs*8];
        }
    }
}

// ---------------------------------------------------------------------------
// K3: QKV MFMA GEMM -> q/k/v in attention frag-chunk layouts (same as R4/R5).
// ---------------------------------------------------------------------------
__global__ __launch_bounds__(256) void qkv_mfma_kernel(
    const unsigned short* __restrict__ xnT, const unsigned short* __restrict__ wbf,
    const float* __restrict__ b_qkv,
    unsigned short* __restrict__ qsw, unsigned short* __restrict__ ksw,
    unsigned short* __restrict__ vsw)
{
    const int tid  = threadIdx.x;
    const int wave = tid >> 6, lane = tid & 63;
    const int lrow = lane & 15, quad = lane >> 4;
    const int R0   = blockIdx.x * 128;
    const int b    = blockIdx.x >> 5;
    const int nb0  = (blockIdx.x & 31) * 128;
    const int oBase = blockIdx.y * 64;
    const int which = oBase >> 8;
    const int o0l   = oBase & 255;
    const bool isV  = (which == 2);
    const int wn = wave >> 1, wo = wave & 1;

    const unsigned short* Abase;
    const unsigned short* Bbase;
    if (!isV) {
        Abase = wbf + ((size_t)(oBase + lrow))*CC + quad*8;
        Bbase = xnT + ((size_t)(R0 + wave*32 + lrow))*CC + quad*8;
    } else {
        Abase = xnT + ((size_t)(R0 + wn*64 + lrow))*CC + quad*8;
        Bbase = wbf + ((size_t)(oBase + wo*32 + lrow))*CC + quad*8;
    }

    f32x4 acc[4][2];
    for (int s = 0; s < 4; s++) for (int t = 0; t < 2; t++)
        acc[s][t] = (f32x4){0.f, 0.f, 0.f, 0.f};

    for (int c0 = 0; c0 < CC; c0 += 32) {
        bf16x8 af[4], bfr[2];
        for (int s = 0; s < 4; s++) af[s]  = *(const bf16x8*)(Abase + s*16*CC + c0);
        for (int t = 0; t < 2; t++) bfr[t] = *(const bf16x8*)(Bbase + t*16*CC + c0);
        for (int s = 0; s < 4; s++)
            for (int t = 0; t < 2; t++)
                acc[s][t] = __builtin_amdgcn_mfma_f32_16x16x32_bf16(af[s], bfr[t], acc[s][t], 0, 0, 0);
    }

    __shared__ unsigned short lds[8192];

    if (!isV) {
        const float sc = (which == 0) ? SCALE : 1.0f;
        for (int s = 0; s < 4; s++) {
            float bias[4];
            for (int r = 0; r < 4; r++) bias[r] = b_qkv[oBase + s*16 + quad*4 + r];
            for (int t = 0; t < 2; t++) {
                us4 h;
                h.x = f2bf((acc[s][t][0] + bias[0]) * sc);
                h.y = f2bf((acc[s][t][1] + bias[1]) * sc);
                h.z = f2bf((acc[s][t][2] + bias[2]) * sc);
                h.w = f2bf((acc[s][t][3] + bias[3]) * sc);
                int chunk = (wave*2 + t)*2 + (s>>1);
                int pos = (((s*2 + (quad>>1)) & 3)*16 + lrow)*8 + (quad&1)*4;
                *(us4*)&lds[chunk*512 + pos] = h;
            }
        }
    } else {
        for (int s = 0; s < 4; s++)
            for (int t = 0; t < 2; t++) {
                int oc = o0l + wo*32 + t*16 + lrow;
                float bias = b_qkv[512 + oc];
                us4 h;
                h.x = f2bf(acc[s][t][0] + bias);
                h.y = f2bf(acc[s][t][1] + bias);
                h.z = f2bf(acc[s][t][2] + bias);
                h.w = f2bf(acc[s][t][3] + bias);
                int chunk = (wn*2 + (s>>1))*4 + wo*2 + t;
                int pos = (((s&1)*2 + (quad>>1))*16 + lrow)*8 + (quad&1)*4;
                *(us4*)&lds[chunk*512 + pos] = h;
            }
    }
    __syncthreads();

    if (!isV) {
        unsigned short* dst = (which == 0) ? qsw : ksw;
        for (int it = 0; it < 4; it++) {
            int f = it*4 + (tid>>6);
            int ng_l = f >> 1, kk_l = f & 1;
            size_t off = ((size_t)(b*256 + (nb0>>4) + ng_l)*8 + (o0l>>5) + kk_l)*512 + lane*8;
            *(bf16x8*)(dst + off) = *(const bf16x8*)&lds[f*512 + lane*8];
        }
    } else {
        for (int it = 0; it < 4; it++) {
            int f = it*4 + (tid>>6);
            int jg_l = f >> 2, ns_l = f & 3;
            size_t off = ((size_t)(b*128 + (nb0>>5) + jg_l)*16 + (o0l>>4) + ns_l)*512 + lane*8;
            *(bf16x8*)(vsw + off) = *(const bf16x8*)&lds[f*512 + lane*8];
        }
    }
}

// ---------------------------------------------------------------------------
// K4: MFMA flash attention v6.
//  - S^T orientation: A=K-frags, B=Q-frags -> D rows=keys, cols=queries.
//    Lane (quad,lrow), reg r holds S[key=jg*16+quad*4+r][query=g*16+lrow]:
//    4 consecutive keys/lane -> P writes are 4 packed ds_write_b64.
//  - async global_load_lds staging: V double-buffered (DMA overlaps S-phase),
//    K single-buffered (DMA overlaps PV). 2 barriers/tile, both covering DMA.
//  - fixed-max softmax, per-lane l partials (reduce = 2 shuffles over quads).
// ---------------------------------------------------------------------------
__global__ __launch_bounds__(256, 2) void attn_mfma_kernel(
    const unsigned short* __restrict__ qsw, const unsigned short* __restrict__ ksw,
    const unsigned short* __restrict__ vsw,
    unsigned short* __restrict__ opart, float* __restrict__ lpart)
{
    const int tid  = threadIdx.x;
    const int wave = tid >> 6, lane = tid & 63;
    const int lrow = lane & 15, quad = lane >> 4;
    const int bx    = blockIdx.x;
    const int split = bx & 3;
    const int ig    = (bx >> 2) & 31;
    const int b     = bx >> 7;
    const int i0w   = ig*128 + wave*32;
    const int koff  = split * (NN / NSPLIT);   // 0,1024,2048,3072
    const int NT    = (NN / NSPLIT) / 32;      // 32 tiles

    __shared__ unsigned short ldsK[8192];          // 16 KB: K tile (single buf)
    __shared__ unsigned short ldsV[2][8192];       // 32 KB: V double buf
    __shared__ unsigned short ldsP[4][32*PSTR];    // 10 KB

    // Q frags (used as B-operand; A/B frag layouts are identical)
    bf16x8 qf[2][8];
    {
        const unsigned short* qb = qsw + ((size_t)b << 20) + (size_t)i0w*256 + lane*8;
        for (int g = 0; g < 2; g++)
            for (int kk = 0; kk < 8; kk++)
                qf[g][kk] = *(const bf16x8*)(qb + g*4096 + kk*512);
    }

    f32x4 o_acc[2][16];
    for (int g = 0; g < 2; g++)
        for (int ns = 0; ns < 16; ns++)
            o_acc[g][ns] = (f32x4){0.f, 0.f, 0.f, 0.f};
    float lsum[2] = {0.f, 0.f};

    // per-lane source pointers (chunk-linear; tile stride 8192 us)
    const unsigned short* kp = ksw + ((size_t)b << 20) + (size_t)koff*256 + wave*2048 + lane*8;
    const unsigned short* vp = vsw + ((size_t)b << 20) + (size_t)koff*256 + wave*2048 + lane*8;

    // preload tile 0 (K + V) via DMA
    for (int t = 0; t < 4; t++) {
        async16(kp + t*512, ldsK + wave*2048 + t*512);
        async16(vp + t*512, ldsV[0] + wave*2048 + t*512);
    }
    __syncthreads();

    for (int jt = 0; jt < NT; jt++) {
        const int cur = jt & 1, nxt = cur ^ 1;

        // async V(t+1) -> other buffer (flies during S-phase)
        if (jt + 1 < NT)
            for (int t = 0; t < 4; t++)
                async16(vp + (size_t)(jt+1)*8192 + t*512, ldsV[nxt] + wave*2048 + t*512);

        // ---- S^T = K Q^T
        f32x4 s[2][2];   // [jg key-group][g query-group]
        for (int jg = 0; jg < 2; jg++)
            for (int g = 0; g < 2; g++)
                s[jg][g] = (f32x4){0.f, 0.f, 0.f, 0.f};
        for (int jg = 0; jg < 2; jg++)
            for (int kk = 0; kk < 8; kk++) {
                bf16x8 kf = *(const bf16x8*)(ldsK + (jg*8 + kk)*512 + lane*8);
                s[jg][0] = __builtin_amdgcn_mfma_f32_16x16x32_bf16(kf, qf[0][kk], s[jg][0], 0, 0, 0);
                s[jg][1] = __builtin_amdgcn_mfma_f32_16x16x32_bf16(kf, qf[1][kk], s[jg][1], 0, 0, 0);
            }

        // ---- p = exp(s); packed b64 P writes; per-lane l partials
        unsigned short* pw = ldsP[wave];
        for (int jg = 0; jg < 2; jg++)
            for (int g = 0; g < 2; g++) {
                float p0 = __expf(s[jg][g][0]);
                float p1 = __expf(s[jg][g][1]);
                float p2 = __expf(s[jg][g][2]);
                float p3 = __expf(s[jg][g][3]);
                lsum[g] += p0 + p1 + p2 + p3;
                us4 h = { f2bf(p0), f2bf(p1), f2bf(p2), f2bf(p3) };
                *(us4*)(pw + (g*16 + lrow)*PSTR + jg*16 + quad*4) = h;
            }

        __syncthreads();   // all waves done with K(t); drains pending DMA

        // async K(t+1) -> single K buffer (flies during PV)
        if (jt + 1 < NT)
            for (int t = 0; t < 4; t++)
                async16(kp + (size_t)(jt+1)*8192 + t*512, ldsK + wave*2048 + t*512);

        // P A-frags: b128 per query-group (rows 80 B apart -> 16B aligned)
        bf16x8 pa[2];
        for (int g = 0; g < 2; g++)
            pa[g] = *(const bf16x8*)(pw + (g*16 + lrow)*PSTR + quad*8);

        // ---- PV from V[cur]
        const unsigned short* lv = ldsV[cur];
        for (int ns = 0; ns < 16; ns++) {
            bf16x8 vf = *(const bf16x8*)(lv + ns*512 + lane*8);
            o_acc[0][ns] = __builtin_amdgcn_mfma_f32_16x16x32_bf16(pa[0], vf, o_acc[0][ns], 0, 0, 0);
            o_acc[1][ns] = __builtin_amdgcn_mfma_f32_16x16x32_bf16(pa[1], vf, o_acc[1][ns], 0, 0, 0);
        }
        __syncthreads();   // drains K(t+1) DMA; V(nxt) visible; P reusable
    }

    // l reduce: queries live on lrow, keys partitioned over quads -> 2 shuffles
    for (int g = 0; g < 2; g++) {
        float v = lsum[g];
        v += __shfl_xor(v, 16);
        v += __shfl_xor(v, 32);
        lsum[g] = v;
    }

    // epilogue: bounce O through LDS into frag-chunk layout, store b128.
    // o_acc[g][ns][r]: query = i0w + g*16 + quad*4 + r, channel = ns*16 + lrow
    unsigned short* reg = &ldsV[0][0] + wave*4096;   // private 4096-us region
    const size_t planeb = ((size_t)(split*BB + b)) << 20;
    for (int g = 0; g < 2; g++) {
        for (int ns = 0; ns < 16; ns++) {
            int kk = ns >> 1;
            int posbase = ((ns & 1)*2 + (lrow >> 3))*128 + (lrow & 7) + quad*32;
            for (int r = 0; r < 4; r++)
                reg[kk*512 + posbase + r*8] = f2bf(o_acc[g][ns][r]);
        }
        unsigned short* dst = opart + planeb + ((size_t)((i0w >> 4) + g))*4096;
        for (int kk = 0; kk < 8; kk++)
            *(bf16x8*)(dst + kk*512 + lane*8) = *(const bf16x8*)(reg + kk*512 + lane*8);
    }
    if (quad == 0)
        for (int g = 0; g < 2; g++)
            lpart[(size_t)(split*BB + b)*NN + i0w + g*16 + lrow] = lsum[g];
}

// ---------------------------------------------------------------------------
// K5: proj MFMA + 4-way split-combine + bias + residual.
// ---------------------------------------------------------------------------
__global__ __launch_bounds__(256) void proj_mfma_kernel(
    const unsigned short* __restrict__ opart, const float* __restrict__ lpart,
    const unsigned short* __restrict__ w2bf, const float* __restrict__ b_proj,
    const float* __restrict__ x, float* __restrict__ out)
{
    const int tid  = threadIdx.x;
    const int wave = tid >> 6, lane = tid & 63;
    const int lrow = lane & 15, quad = lane >> 4;
    const int b    = blockIdx.x >> 5;
    const int nb0  = (blockIdx.x & 31) * 128;
    const int oBase = blockIdx.y * 64;
    const int wn = wave >> 1, wo = wave & 1;

    float sinv[4];
    for (int s = 0; s < 4; s++) {
        int n = nb0 + wn*64 + s*16 + lrow;
        float l = 0.f;
        for (int sp = 0; sp < NSPLIT; sp++)
            l += lpart[(size_t)(sp*BB + b)*NN + n];
        sinv[s] = 1.0f / l;
    }

    const int rgl = (nb0 >> 4) + wn*4;
    const unsigned short* Bb = w2bf + ((size_t)(oBase + wo*32 + lrow))*CC + quad*8;

    f32x4 acc[4][2];
    for (int s = 0; s < 4; s++) for (int t = 0; t < 2; t++)
        acc[s][t] = (f32x4){0.f, 0.f, 0.f, 0.f};

    const size_t pstride = (size_t)BB << 20;
    const unsigned short* Ab = opart + ((size_t)b << 20) + (size_t)rgl*4096 + lane*8;

    for (int c0 = 0; c0 < CC; c0 += 32) {
        const int kk = c0 >> 5;
        bf16x8 af[4], bfr[2];
        for (int s = 0; s < 4; s++) {
            const unsigned short* a0 = Ab + (size_t)s*4096 + kk*512;
            bf16x8 u0 = *(const bf16x8*)(a0);
            bf16x8 u1 = *(const bf16x8*)(a0 + pstride);
            bf16x8 u2 = *(const bf16x8*)(a0 + 2*pstride);
            bf16x8 u3 = *(const bf16x8*)(a0 + 3*pstride);
            for (int e = 0; e < 8; e++)
                af[s][e] = (short)f2bf((bf2f(u0[e]) + bf2f(u1[e]) + bf2f(u2[e]) + bf2f(u3[e])) * sinv[s]);
        }
        for (int t = 0; t < 2; t++) bfr[t] = *(const bf16x8*)(Bb + t*16*CC + c0);
        for (int s = 0; s < 4; s++)
            for (int t = 0; t < 2; t++)
                acc[s][t] = __builtin_amdgcn_mfma_f32_16x16x32_bf16(af[s], bfr[t], acc[s][t], 0, 0, 0);
    }

    for (int s = 0; s < 4; s++)
        for (int t = 0; t < 2; t++) {
            int o = oBase + wo*32 + t*16 + lrow;
            int n = nb0 + wn*64 + s*16 + quad*4;
            size_t idx = ((size_t)(b*CC + o))*NN + n;
            float bias = b_proj[o];
            float4 xv = *(const float4*)(x + idx);
            float4 ov;
            ov.x = acc[s][t][0] + bias + xv.x;
            ov.y = acc[s][t][1] + bias + xv.y;
            ov.z = acc[s][t][2] + bias + xv.z;
            ov.w = acc[s][t][3] + bias + xv.w;
            *(float4*)(out + idx) = ov;
        }
}

// ---------------------------------------------------------------------------
extern "C" void kernel_launch(void* const* d_in, const int* in_sizes, int n_in,
                              void* d_out, int out_size, void* d_ws, size_t ws_size,
                              hipStream_t stream) {
    const float* x      = (const float*)d_in[0];
    const float* gamma  = (const float*)d_in[1];
    const float* beta   = (const float*)d_in[2];
    const float* w_qkv  = (const float*)d_in[3];
    const float* b_qkv  = (const float*)d_in[4];
    const float* w_proj = (const float*)d_in[5];
    const float* b_proj = (const float*)d_in[6];
    float* out = (float*)d_out;

    const size_t plane = (size_t)BB * NN * CC;     // 4,194,304 elems
    unsigned short* xnT = (unsigned short*)d_ws;
    unsigned short* qsw = xnT + plane;
    unsigned short* ksw = qsw + plane;
    unsigned short* vsw = ksw + plane;
    unsigned short* wbf = vsw + plane;             // 262144 us
    unsigned short* opart = wbf + 262144;          // NSPLIT*plane us (bf16)
    float* lpart    = (float*)(opart + (size_t)NSPLIT*plane);  // NSPLIT*BB*NN
    float* partials = lpart + (size_t)NSPLIT*BB*NN;
    float* stats    = partials + 512;

    prep_kernel<<<512, 256, 0, stream>>>(x, w_qkv, w_proj, partials, wbf);
    gn_stats2_kernel<<<1, 64, 0, stream>>>(partials, stats);

    dim3 gnt(64, 4, BB);
    norm_t_kernel<<<gnt, 256, 0, stream>>>(x, gamma, beta, stats, xnT);

    dim3 gq(128, 12);
    qkv_mfma_kernel<<<gq, 256, 0, stream>>>(xnT, wbf, b_qkv, qsw, ksw, vsw);

    attn_mfma_kernel<<<BB*32*NSPLIT, 256, 0, stream>>>(qsw, ksw, vsw, opart, lpart);

    dim3 gp(128, 4);
    proj_mfma_kernel<<<gp, 256, 0, stream>>>(opart, lpart, wbf + 196608, b_proj, x, out);
}